// Round 1
// baseline (1191.515 us; speedup 1.0000x reference)
//
#include <hip/hip_runtime.h>
#include <hip/hip_bf16.h>
#include <cstdint>

// GraphTransformerLinkPredictor on MI355X.
// Structure: pe proj -> fused input proj -> 2x { gemm4 (q,k,v,skip) -> fused
// edge attention+aggregate+LN } -> pair dot + sigmoid.
// Softmax identity: alpha = exp(s)/sum(exp(s)) with no max-subtraction
// (scores bounded ~O(1)); agg = sum(exp(s)*v)/sum(exp(s)) in one CSR pass.
// q,k stored bf16 (score-only, error ~1e-3 << 2e-2 tol); h,v,skip fp32.

#define NN      100000
#define EE      1000000
#define HIDC    128
#define RWSEC   16
#define WALKC   16
#define NPAIRSC 200000

typedef unsigned int       u32;
typedef unsigned short     u16;

__device__ __forceinline__ float bflo(u32 u){ return __uint_as_float(u << 16); }
__device__ __forceinline__ float bfhi(u32 u){ return __uint_as_float(u & 0xffff0000u); }
__device__ __forceinline__ u16 f2bf(float f){
    u32 u = __float_as_uint(f);
    u += 0x7fffu + ((u >> 16) & 1u);   // round-to-nearest-even
    return (u16)(u >> 16);
}

// ---------------- RWSE projection: pe[N,16] = rw[N,16] @ W[16,16] + b ----------------
__global__ __launch_bounds__(256) void pe_kernel(const float* __restrict__ rw,
                                                 const float* __restrict__ Wr,
                                                 const float* __restrict__ br,
                                                 float* __restrict__ pe){
    int idx = blockIdx.x * 256 + threadIdx.x;
    if (idx >= NN * RWSEC) return;
    int n = idx >> 4, j = idx & 15;
    const float* r = rw + (size_t)n * WALKC;
    float s = br[j];
    #pragma unroll
    for (int w = 0; w < WALKC; ++w) s = fmaf(r[w], Wr[w * RWSEC + j], s);
    pe[idx] = s;
}

// ---------------- input proj: h[N,128] = concat(x,pe)[N,144] @ W_in + b_in ----------------
__global__ __launch_bounds__(256) void inproj_kernel(const float* __restrict__ x,
                                                     const float* __restrict__ pe,
                                                     const float* __restrict__ Win,
                                                     const float* __restrict__ bin,
                                                     float* __restrict__ h){
    __shared__ float xs[32 * 144];
    int tid = threadIdx.x;
    int n0  = blockIdx.x * 32;
    #pragma unroll
    for (int k = 0; k < 16; ++k){            // 32*128 = 4096 x-values
        int idx = tid + k * 256;
        int n = idx >> 7, i = idx & 127;
        xs[n * 144 + i] = x[(size_t)(n0 + n) * 128 + i];
    }
    #pragma unroll
    for (int k = 0; k < 2; ++k){             // 32*16 = 512 pe-values
        int id = tid + k * 256;
        int n = id >> 4, j = id & 15;
        xs[n * 144 + 128 + j] = pe[(size_t)(n0 + n) * 16 + j];
    }
    __syncthreads();
    int c = tid & 127, ng = tid >> 7;        // 2 node-groups of 16
    float acc[16];
    #pragma unroll
    for (int n = 0; n < 16; ++n) acc[n] = 0.f;
    for (int i4 = 0; i4 < 36; ++i4){
        int i = i4 * 4;
        float w0 = Win[(i + 0) * 128 + c];
        float w1 = Win[(i + 1) * 128 + c];
        float w2 = Win[(i + 2) * 128 + c];
        float w3 = Win[(i + 3) * 128 + c];
        #pragma unroll
        for (int n = 0; n < 16; ++n){
            const float4 hv = *reinterpret_cast<const float4*>(&xs[(ng * 16 + n) * 144 + i]);
            acc[n] = fmaf(hv.x, w0, fmaf(hv.y, w1, fmaf(hv.z, w2, fmaf(hv.w, w3, acc[n]))));
        }
    }
    float bb = bin[c];
    #pragma unroll
    for (int n = 0; n < 16; ++n)
        h[(size_t)(n0 + ng * 16 + n) * 128 + c] = acc[n] + bb;
}

// ---------------- CSR build over col ----------------
__global__ __launch_bounds__(256) void deg_kernel(const int* __restrict__ col,
                                                  int* __restrict__ deg){
    int e = blockIdx.x * 256 + threadIdx.x;
    if (e < EE) atomicAdd(&deg[col[e]], 1);
}

__global__ __launch_bounds__(1024) void scan_kernel(const int* __restrict__ deg,
                                                    int* __restrict__ offs,
                                                    int* __restrict__ cursor){
    __shared__ int lds[1024];
    int tid = threadIdx.x;
    const int chunk = (NN + 1023) / 1024;    // 98
    int base = tid * chunk;
    int s = 0;
    for (int j = 0; j < chunk; ++j){ int idx = base + j; if (idx < NN) s += deg[idx]; }
    lds[tid] = s; __syncthreads();
    for (int off = 1; off < 1024; off <<= 1){
        int v = (tid >= off) ? lds[tid - off] : 0;
        __syncthreads();
        lds[tid] += v;
        __syncthreads();
    }
    int run = lds[tid] - s;                  // exclusive prefix
    for (int j = 0; j < chunk; ++j){
        int idx = base + j;
        if (idx < NN){ offs[idx] = run; cursor[idx] = run; run += deg[idx]; }
    }
}

__global__ __launch_bounds__(256) void fill_kernel(const int* __restrict__ ei,
                                                   int* __restrict__ cursor,
                                                   int* __restrict__ ebuf){
    int e = blockIdx.x * 256 + threadIdx.x;
    if (e < EE){
        int c = ei[EE + e];                  // col (target)
        int p = atomicAdd(&cursor[c], 1);
        ebuf[p] = ei[e];                     // row (source)
    }
}

// ---------------- per-layer fused GEMM: q,k (bf16) and v,skip (fp32) ----------------
__global__ __launch_bounds__(256) void gemm4_kernel(const float* __restrict__ h,
        const float* __restrict__ Wq, const float* __restrict__ bq,
        const float* __restrict__ Wk, const float* __restrict__ bk,
        const float* __restrict__ Wv, const float* __restrict__ bv,
        const float* __restrict__ Ws, const float* __restrict__ bs,
        u16* __restrict__ qb, u16* __restrict__ kb,
        float* __restrict__ vf, float* __restrict__ sf){
    __shared__ float hs[32 * 128];           // 16 KB
    int tid = threadIdx.x;
    int n0  = blockIdx.x * 32;
    #pragma unroll
    for (int k = 0; k < 16; ++k){
        int idx = tid + k * 256;
        hs[idx] = h[(size_t)n0 * 128 + idx];
    }
    __syncthreads();
    int  c  = tid & 127;
    bool lo = tid < 128;
    const float* WA = lo ? Wq : Wk;
    const float* WB = lo ? Wv : Ws;
    float accA[32], accB[32];
    #pragma unroll
    for (int n = 0; n < 32; ++n){ accA[n] = 0.f; accB[n] = 0.f; }
    for (int i4 = 0; i4 < 32; ++i4){
        int i = i4 * 4;
        float a0 = WA[(i + 0) * 128 + c], a1 = WA[(i + 1) * 128 + c];
        float a2 = WA[(i + 2) * 128 + c], a3 = WA[(i + 3) * 128 + c];
        float b0 = WB[(i + 0) * 128 + c], b1 = WB[(i + 1) * 128 + c];
        float b2 = WB[(i + 2) * 128 + c], b3 = WB[(i + 3) * 128 + c];
        #pragma unroll
        for (int n = 0; n < 32; ++n){
            const float4 hv = *reinterpret_cast<const float4*>(&hs[n * 128 + i]);
            accA[n] = fmaf(hv.x, a0, fmaf(hv.y, a1, fmaf(hv.z, a2, fmaf(hv.w, a3, accA[n]))));
            accB[n] = fmaf(hv.x, b0, fmaf(hv.y, b1, fmaf(hv.z, b2, fmaf(hv.w, b3, accB[n]))));
        }
    }
    float biasA = lo ? bq[c] : bk[c];
    float biasB = lo ? bv[c] : bs[c];
    u16*   qk = lo ? qb : kb;
    float* vs = lo ? vf : sf;
    #pragma unroll
    for (int n = 0; n < 32; ++n){
        qk[(size_t)(n0 + n) * 128 + c] = f2bf(accA[n] + biasA);
        vs[(size_t)(n0 + n) * 128 + c] = accB[n] + biasB;
    }
}

// ---------------- fused edge attention + aggregate + skip + residual + LN + ReLU ----------------
// one wave per target node; lane owns dims {2*lane, 2*lane+1}; 16-lane groups = heads
__global__ __launch_bounds__(256) void attn_kernel(float* __restrict__ h,
        const u16* __restrict__ qb, const u16* __restrict__ kb,
        const float* __restrict__ vf, const float* __restrict__ sf,
        const int* __restrict__ offs, const int* __restrict__ deg,
        const int* __restrict__ ebuf,
        const float* __restrict__ g, const float* __restrict__ bta){
    int tid  = threadIdx.x;
    int lane = tid & 63;
    int n    = blockIdx.x * 4 + (tid >> 6);
    const u32 qu = *reinterpret_cast<const u32*>(qb + (size_t)n * 128 + lane * 2);
    float q0 = bflo(qu), q1 = bfhi(qu);
    int beg = offs[n], cnt = deg[n];
    float z = 0.f, a0 = 0.f, a1 = 0.f;
    const float scale = 0.17677669529663687f;   // 1/sqrt(32)
    for (int t = 0; t < cnt; ++t){
        int r = ebuf[beg + t];
        u32 ku = *reinterpret_cast<const u32*>(kb + (size_t)r * 128 + lane * 2);
        float s = q0 * bflo(ku) + q1 * bfhi(ku);
        s += __shfl_xor(s, 1); s += __shfl_xor(s, 2);
        s += __shfl_xor(s, 4); s += __shfl_xor(s, 8);   // per-head (16-lane) sum
        float ex = __expf(s * scale);
        const float2 v2 = *reinterpret_cast<const float2*>(vf + (size_t)r * 128 + lane * 2);
        z += ex;
        a0 = fmaf(ex, v2.x, a0);
        a1 = fmaf(ex, v2.y, a1);
    }
    float rz = (cnt > 0) ? 1.f / z : 0.f;
    size_t p0 = (size_t)n * 128 + lane * 2;
    float y0 = h[p0]     + a0 * rz + sf[p0];
    float y1 = h[p0 + 1] + a1 * rz + sf[p0 + 1];
    float sum = y0 + y1, sq = y0 * y0 + y1 * y1;
    #pragma unroll
    for (int m = 1; m < 64; m <<= 1){
        sum += __shfl_xor(sum, m);
        sq  += __shfl_xor(sq,  m);
    }
    float mu  = sum * (1.f / 128.f);
    float var = sq * (1.f / 128.f) - mu * mu;
    var = var < 0.f ? 0.f : var;
    float inv = rsqrtf(var + 1e-5f);
    int c = lane * 2;
    float o0 = fmaf(g[c]     * (y0 - mu), inv, bta[c]);
    float o1 = fmaf(g[c + 1] * (y1 - mu), inv, bta[c + 1]);
    h[p0]     = o0 > 0.f ? o0 : 0.f;
    h[p0 + 1] = o1 > 0.f ? o1 : 0.f;
}

// ---------------- link prediction: sigmoid(h[src] . h[dst]) ----------------
__global__ __launch_bounds__(256) void pair_kernel(const float* __restrict__ h,
                                                   const int* __restrict__ src,
                                                   const int* __restrict__ dst,
                                                   float* __restrict__ out){
    int tid = threadIdx.x;
    int pid = blockIdx.x * 16 + (tid >> 4);
    int sub = tid & 15;
    int s = src[pid], d = dst[pid];
    const float4* A = reinterpret_cast<const float4*>(h + (size_t)s * 128 + sub * 8);
    const float4* B = reinterpret_cast<const float4*>(h + (size_t)d * 128 + sub * 8);
    float4 a0 = A[0], a1 = A[1], b0 = B[0], b1 = B[1];
    float dot = a0.x * b0.x + a0.y * b0.y + a0.z * b0.z + a0.w * b0.w
              + a1.x * b1.x + a1.y * b1.y + a1.z * b1.z + a1.w * b1.w;
    dot += __shfl_xor(dot, 1); dot += __shfl_xor(dot, 2);
    dot += __shfl_xor(dot, 4); dot += __shfl_xor(dot, 8);
    if (sub == 0) out[pid] = 1.f / (1.f + __expf(-dot));
}

extern "C" void kernel_launch(void* const* d_in, const int* in_sizes, int n_in,
                              void* d_out, int out_size, void* d_ws, size_t ws_size,
                              hipStream_t stream){
    const float* x      = (const float*)d_in[0];
    const float* rw     = (const float*)d_in[1];
    const int*   ei     = (const int*)  d_in[2];
    const int*   src    = (const int*)  d_in[3];
    const int*   dst    = (const int*)  d_in[4];
    const float* W_rwse = (const float*)d_in[5];
    const float* b_rwse = (const float*)d_in[6];
    const float* W_in   = (const float*)d_in[7];
    const float* b_in   = (const float*)d_in[8];
    const float* Wq     = (const float*)d_in[9];
    const float* bq     = (const float*)d_in[10];
    const float* Wk     = (const float*)d_in[11];
    const float* bk     = (const float*)d_in[12];
    const float* Wv     = (const float*)d_in[13];
    const float* bv     = (const float*)d_in[14];
    const float* Wsk    = (const float*)d_in[15];
    const float* bsk    = (const float*)d_in[16];
    const float* ln_g   = (const float*)d_in[17];
    const float* ln_b   = (const float*)d_in[18];
    float* out = (float*)d_out;

    char* p = (char*)d_ws;
    auto carve = [&](size_t bytes) -> char* {
        char* r = p; p += (bytes + 255) & ~(size_t)255; return r;
    };
    float* h    = (float*)carve((size_t)NN * 128 * 4);   // 51.2 MB
    float* pe   = (float*)carve((size_t)NN * 16 * 4);    //  6.4 MB
    u16*   qb   = (u16*)  carve((size_t)NN * 128 * 2);   // 25.6 MB
    u16*   kb   = (u16*)  carve((size_t)NN * 128 * 2);   // 25.6 MB
    float* vf   = (float*)carve((size_t)NN * 128 * 4);   // 51.2 MB
    float* sf   = (float*)carve((size_t)NN * 128 * 4);   // 51.2 MB
    int*   deg  = (int*)  carve((size_t)NN * 4);
    int*   offs = (int*)  carve((size_t)NN * 4);
    int*   curs = (int*)  carve((size_t)NN * 4);
    int*   ebuf = (int*)  carve((size_t)EE * 4);         //  4.0 MB

    hipMemsetAsync(deg, 0, (size_t)NN * 4, stream);

    pe_kernel<<<(NN * 16 + 255) / 256, 256, 0, stream>>>(rw, W_rwse, b_rwse, pe);
    inproj_kernel<<<NN / 32, 256, 0, stream>>>(x, pe, W_in, b_in, h);
    deg_kernel<<<(EE + 255) / 256, 256, 0, stream>>>(ei + EE, deg);
    scan_kernel<<<1, 1024, 0, stream>>>(deg, offs, curs);
    fill_kernel<<<(EE + 255) / 256, 256, 0, stream>>>(ei, curs, ebuf);

    for (int l = 0; l < 2; ++l){
        gemm4_kernel<<<NN / 32, 256, 0, stream>>>(h,
            Wq + (size_t)l * 16384, bq + l * 128,
            Wk + (size_t)l * 16384, bk + l * 128,
            Wv + (size_t)l * 16384, bv + l * 128,
            Wsk + (size_t)l * 16384, bsk + l * 128,
            qb, kb, vf, sf);
        attn_kernel<<<NN / 4, 256, 0, stream>>>(h, qb, kb, vf, sf,
            offs, deg, ebuf, ln_g + l * 128, ln_b + l * 128);
    }
    pair_kernel<<<NPAIRSC / 16, 256, 0, stream>>>(h, src, dst, out);
}

// Round 2
// 943.995 us; speedup vs baseline: 1.2622x; 1.2622x over previous
//
#include <hip/hip_runtime.h>
#include <hip/hip_bf16.h>
#include <cstdint>

// GraphTransformerLinkPredictor on MI355X.
// Structure: pe proj -> fused input proj -> CSR build (hierarchical scan) ->
// 2x { gemm4 (q,k,v,skip) -> fused edge attention+aggregate+LN } -> pair dot.
// Softmax identity: alpha = exp(s)/sum(exp(s)) (scores bounded, no max pass).
// q,k stored bf16 (score-only); h,v,skip fp32.

#define NN      100000
#define EE      1000000
#define HIDC    128
#define RWSEC   16
#define WALKC   16
#define NPAIRSC 200000
#define SCAN_NB ((NN + 1023) / 1024)   // 98

typedef unsigned int       u32;
typedef unsigned short     u16;

__device__ __forceinline__ float bflo(u32 u){ return __uint_as_float(u << 16); }
__device__ __forceinline__ float bfhi(u32 u){ return __uint_as_float(u & 0xffff0000u); }
__device__ __forceinline__ u16 f2bf(float f){
    u32 u = __float_as_uint(f);
    u += 0x7fffu + ((u >> 16) & 1u);   // round-to-nearest-even
    return (u16)(u >> 16);
}

// ---------------- RWSE projection: pe[N,16] = rw[N,16] @ W[16,16] + b ----------------
__global__ __launch_bounds__(256) void pe_kernel(const float* __restrict__ rw,
                                                 const float* __restrict__ Wr,
                                                 const float* __restrict__ br,
                                                 float* __restrict__ pe){
    int idx = blockIdx.x * 256 + threadIdx.x;
    if (idx >= NN * RWSEC) return;
    int n = idx >> 4, j = idx & 15;
    const float* r = rw + (size_t)n * WALKC;
    float s = br[j];
    #pragma unroll
    for (int w = 0; w < WALKC; ++w) s = fmaf(r[w], Wr[w * RWSEC + j], s);
    pe[idx] = s;
}

// ---------------- input proj: h[N,128] = concat(x,pe)[N,144] @ W_in + b_in ----------------
__global__ __launch_bounds__(256) void inproj_kernel(const float* __restrict__ x,
                                                     const float* __restrict__ pe,
                                                     const float* __restrict__ Win,
                                                     const float* __restrict__ bin,
                                                     float* __restrict__ h){
    __shared__ float xs[32 * 144];
    int tid = threadIdx.x;
    int n0  = blockIdx.x * 32;
    #pragma unroll
    for (int k = 0; k < 16; ++k){            // 32*128 = 4096 x-values
        int idx = tid + k * 256;
        int n = idx >> 7, i = idx & 127;
        xs[n * 144 + i] = x[(size_t)(n0 + n) * 128 + i];
    }
    #pragma unroll
    for (int k = 0; k < 2; ++k){             // 32*16 = 512 pe-values
        int id = tid + k * 256;
        int n = id >> 4, j = id & 15;
        xs[n * 144 + 128 + j] = pe[(size_t)(n0 + n) * 16 + j];
    }
    __syncthreads();
    int c = tid & 127, ng = tid >> 7;        // 2 node-groups of 16
    float acc[16];
    #pragma unroll
    for (int n = 0; n < 16; ++n) acc[n] = 0.f;
    for (int i4 = 0; i4 < 36; ++i4){
        int i = i4 * 4;
        float w0 = Win[(i + 0) * 128 + c];
        float w1 = Win[(i + 1) * 128 + c];
        float w2 = Win[(i + 2) * 128 + c];
        float w3 = Win[(i + 3) * 128 + c];
        #pragma unroll
        for (int n = 0; n < 16; ++n){
            const float4 hv = *reinterpret_cast<const float4*>(&xs[(ng * 16 + n) * 144 + i]);
            acc[n] = fmaf(hv.x, w0, fmaf(hv.y, w1, fmaf(hv.z, w2, fmaf(hv.w, w3, acc[n]))));
        }
    }
    float bb = bin[c];
    #pragma unroll
    for (int n = 0; n < 16; ++n)
        h[(size_t)(n0 + ng * 16 + n) * 128 + c] = acc[n] + bb;
}

// ---------------- CSR build over col ----------------
__global__ __launch_bounds__(256) void deg_kernel(const int* __restrict__ col,
                                                  int* __restrict__ deg){
    int e = blockIdx.x * 256 + threadIdx.x;
    if (e < EE) atomicAdd(&deg[col[e]], 1);
}

// 3-level scan: per-block sums -> scan of partials -> per-block scan + base
__global__ __launch_bounds__(1024) void scan1_kernel(const int* __restrict__ deg,
                                                     int* __restrict__ partial){
    __shared__ int lds[16];
    int tid = threadIdx.x;
    int i = blockIdx.x * 1024 + tid;
    int v = (i < NN) ? deg[i] : 0;
    #pragma unroll
    for (int m = 1; m < 64; m <<= 1) v += __shfl_xor(v, m);
    if ((tid & 63) == 0) lds[tid >> 6] = v;
    __syncthreads();
    if (tid < 16){
        int s = lds[tid];
        #pragma unroll
        for (int m = 1; m < 16; m <<= 1) s += __shfl_xor(s, m, 16);
        if (tid == 0) partial[blockIdx.x] = s;
    }
}

__global__ __launch_bounds__(128) void scan2_kernel(const int* __restrict__ partial,
                                                    int* __restrict__ ppref){
    __shared__ int lds[128];
    int tid = threadIdx.x;
    int v = (tid < SCAN_NB) ? partial[tid] : 0;
    lds[tid] = v;
    __syncthreads();
    for (int off = 1; off < 128; off <<= 1){
        int y = (tid >= off) ? lds[tid - off] : 0;
        __syncthreads();
        lds[tid] += y;
        __syncthreads();
    }
    if (tid < SCAN_NB) ppref[tid] = lds[tid] - v;   // exclusive prefix
}

__global__ __launch_bounds__(1024) void scan3_kernel(const int* __restrict__ deg,
                                                     const int* __restrict__ ppref,
                                                     int* __restrict__ offs,
                                                     int* __restrict__ cursor){
    __shared__ int wsum[16];
    int tid = threadIdx.x, lane = tid & 63, wid = tid >> 6;
    int i = blockIdx.x * 1024 + tid;
    int v = (i < NN) ? deg[i] : 0;
    int x = v;
    #pragma unroll
    for (int off = 1; off < 64; off <<= 1){
        int y = __shfl_up(x, off);
        if (lane >= off) x += y;
    }
    if (lane == 63) wsum[wid] = x;
    __syncthreads();
    if (tid < 16){
        int s = wsum[tid];
        int t = s;
        #pragma unroll
        for (int off = 1; off < 16; off <<= 1){
            int y = __shfl_up(t, off, 16);
            if (tid >= off) t += y;
        }
        wsum[tid] = t - s;                   // exclusive wave base
    }
    __syncthreads();
    int base = ppref[blockIdx.x] + wsum[wid] + (x - v);   // global exclusive prefix
    if (i < NN){ offs[i] = base; cursor[i] = base; }
}

__global__ __launch_bounds__(256) void fill_kernel(const int* __restrict__ ei,
                                                   int* __restrict__ cursor,
                                                   int* __restrict__ ebuf){
    int e = blockIdx.x * 256 + threadIdx.x;
    if (e < EE){
        int c = ei[EE + e];                  // col (target)
        int p = atomicAdd(&cursor[c], 1);
        ebuf[p] = ei[e];                     // row (source)
    }
}

// ---------------- per-layer fused GEMM: q,k (bf16) and v,skip (fp32) ----------------
__global__ __launch_bounds__(256) void gemm4_kernel(const float* __restrict__ h,
        const float* __restrict__ Wq, const float* __restrict__ bq,
        const float* __restrict__ Wk, const float* __restrict__ bk,
        const float* __restrict__ Wv, const float* __restrict__ bv,
        const float* __restrict__ Ws, const float* __restrict__ bs,
        u16* __restrict__ qb, u16* __restrict__ kb,
        float* __restrict__ vf, float* __restrict__ sf){
    __shared__ float hs[32 * 128];           // 16 KB
    int tid = threadIdx.x;
    int n0  = blockIdx.x * 32;
    #pragma unroll
    for (int k = 0; k < 16; ++k){
        int idx = tid + k * 256;
        hs[idx] = h[(size_t)n0 * 128 + idx];
    }
    __syncthreads();
    int  c  = tid & 127;
    bool lo = tid < 128;
    const float* WA = lo ? Wq : Wk;
    const float* WB = lo ? Wv : Ws;
    float accA[32], accB[32];
    #pragma unroll
    for (int n = 0; n < 32; ++n){ accA[n] = 0.f; accB[n] = 0.f; }
    for (int i4 = 0; i4 < 32; ++i4){
        int i = i4 * 4;
        float a0 = WA[(i + 0) * 128 + c], a1 = WA[(i + 1) * 128 + c];
        float a2 = WA[(i + 2) * 128 + c], a3 = WA[(i + 3) * 128 + c];
        float b0 = WB[(i + 0) * 128 + c], b1 = WB[(i + 1) * 128 + c];
        float b2 = WB[(i + 2) * 128 + c], b3 = WB[(i + 3) * 128 + c];
        #pragma unroll
        for (int n = 0; n < 32; ++n){
            const float4 hv = *reinterpret_cast<const float4*>(&hs[n * 128 + i]);
            accA[n] = fmaf(hv.x, a0, fmaf(hv.y, a1, fmaf(hv.z, a2, fmaf(hv.w, a3, accA[n]))));
            accB[n] = fmaf(hv.x, b0, fmaf(hv.y, b1, fmaf(hv.z, b2, fmaf(hv.w, b3, accB[n]))));
        }
    }
    float biasA = lo ? bq[c] : bk[c];
    float biasB = lo ? bv[c] : bs[c];
    u16*   qk = lo ? qb : kb;
    float* vs = lo ? vf : sf;
    #pragma unroll
    for (int n = 0; n < 32; ++n){
        qk[(size_t)(n0 + n) * 128 + c] = f2bf(accA[n] + biasA);
        vs[(size_t)(n0 + n) * 128 + c] = accB[n] + biasB;
    }
}

// ---------------- fused edge attention + aggregate + skip + residual + LN + ReLU ----------------
// one wave per target node; lane owns dims {2*lane, 2*lane+1}; 16-lane groups = heads
__global__ __launch_bounds__(256) void attn_kernel(float* __restrict__ h,
        const u16* __restrict__ qb, const u16* __restrict__ kb,
        const float* __restrict__ vf, const float* __restrict__ sf,
        const int* __restrict__ offs, const int* __restrict__ deg,
        const int* __restrict__ ebuf,
        const float* __restrict__ g, const float* __restrict__ bta){
    int tid  = threadIdx.x;
    int lane = tid & 63;
    int n    = blockIdx.x * 4 + (tid >> 6);
    const u32 qu = *reinterpret_cast<const u32*>(qb + (size_t)n * 128 + lane * 2);
    float q0 = bflo(qu), q1 = bfhi(qu);
    int beg = offs[n], cnt = deg[n];
    float z = 0.f, a0 = 0.f, a1 = 0.f;
    const float scale = 0.17677669529663687f;   // 1/sqrt(32)
    for (int t = 0; t < cnt; ++t){
        int r = ebuf[beg + t];
        u32 ku = *reinterpret_cast<const u32*>(kb + (size_t)r * 128 + lane * 2);
        float s = q0 * bflo(ku) + q1 * bfhi(ku);
        s += __shfl_xor(s, 1); s += __shfl_xor(s, 2);
        s += __shfl_xor(s, 4); s += __shfl_xor(s, 8);   // per-head (16-lane) sum
        float ex = __expf(s * scale);
        const float2 v2 = *reinterpret_cast<const float2*>(vf + (size_t)r * 128 + lane * 2);
        z += ex;
        a0 = fmaf(ex, v2.x, a0);
        a1 = fmaf(ex, v2.y, a1);
    }
    float rz = (cnt > 0) ? 1.f / z : 0.f;
    size_t p0 = (size_t)n * 128 + lane * 2;
    float y0 = h[p0]     + a0 * rz + sf[p0];
    float y1 = h[p0 + 1] + a1 * rz + sf[p0 + 1];
    float sum = y0 + y1, sq = y0 * y0 + y1 * y1;
    #pragma unroll
    for (int m = 1; m < 64; m <<= 1){
        sum += __shfl_xor(sum, m);
        sq  += __shfl_xor(sq,  m);
    }
    float mu  = sum * (1.f / 128.f);
    float var = sq * (1.f / 128.f) - mu * mu;
    var = var < 0.f ? 0.f : var;
    float inv = rsqrtf(var + 1e-5f);
    int c = lane * 2;
    float o0 = fmaf(g[c]     * (y0 - mu), inv, bta[c]);
    float o1 = fmaf(g[c + 1] * (y1 - mu), inv, bta[c + 1]);
    h[p0]     = o0 > 0.f ? o0 : 0.f;
    h[p0 + 1] = o1 > 0.f ? o1 : 0.f;
}

// ---------------- link prediction: sigmoid(h[src] . h[dst]) ----------------
__global__ __launch_bounds__(256) void pair_kernel(const float* __restrict__ h,
                                                   const int* __restrict__ src,
                                                   const int* __restrict__ dst,
                                                   float* __restrict__ out){
    int tid = threadIdx.x;
    int pid = blockIdx.x * 16 + (tid >> 4);
    int sub = tid & 15;
    int s = src[pid], d = dst[pid];
    const float4* A = reinterpret_cast<const float4*>(h + (size_t)s * 128 + sub * 8);
    const float4* B = reinterpret_cast<const float4*>(h + (size_t)d * 128 + sub * 8);
    float4 a0 = A[0], a1 = A[1], b0 = B[0], b1 = B[1];
    float dot = a0.x * b0.x + a0.y * b0.y + a0.z * b0.z + a0.w * b0.w
              + a1.x * b1.x + a1.y * b1.y + a1.z * b1.z + a1.w * b1.w;
    dot += __shfl_xor(dot, 1); dot += __shfl_xor(dot, 2);
    dot += __shfl_xor(dot, 4); dot += __shfl_xor(dot, 8);
    if (sub == 0) out[pid] = 1.f / (1.f + __expf(-dot));
}

extern "C" void kernel_launch(void* const* d_in, const int* in_sizes, int n_in,
                              void* d_out, int out_size, void* d_ws, size_t ws_size,
                              hipStream_t stream){
    const float* x      = (const float*)d_in[0];
    const float* rw     = (const float*)d_in[1];
    const int*   ei     = (const int*)  d_in[2];
    const int*   src    = (const int*)  d_in[3];
    const int*   dst    = (const int*)  d_in[4];
    const float* W_rwse = (const float*)d_in[5];
    const float* b_rwse = (const float*)d_in[6];
    const float* W_in   = (const float*)d_in[7];
    const float* b_in   = (const float*)d_in[8];
    const float* Wq     = (const float*)d_in[9];
    const float* bq     = (const float*)d_in[10];
    const float* Wk     = (const float*)d_in[11];
    const float* bk     = (const float*)d_in[12];
    const float* Wv     = (const float*)d_in[13];
    const float* bv     = (const float*)d_in[14];
    const float* Wsk    = (const float*)d_in[15];
    const float* bsk    = (const float*)d_in[16];
    const float* ln_g   = (const float*)d_in[17];
    const float* ln_b   = (const float*)d_in[18];
    float* out = (float*)d_out;

    char* p = (char*)d_ws;
    auto carve = [&](size_t bytes) -> char* {
        char* r = p; p += (bytes + 255) & ~(size_t)255; return r;
    };
    float* h    = (float*)carve((size_t)NN * 128 * 4);   // 51.2 MB
    float* pe   = (float*)carve((size_t)NN * 16 * 4);    //  6.4 MB
    u16*   qb   = (u16*)  carve((size_t)NN * 128 * 2);   // 25.6 MB
    u16*   kb   = (u16*)  carve((size_t)NN * 128 * 2);   // 25.6 MB
    float* vf   = (float*)carve((size_t)NN * 128 * 4);   // 51.2 MB
    float* sf   = (float*)carve((size_t)NN * 128 * 4);   // 51.2 MB
    int*   deg  = (int*)  carve((size_t)NN * 4);
    int*   offs = (int*)  carve((size_t)NN * 4);
    int*   curs = (int*)  carve((size_t)NN * 4);
    int*   ebuf = (int*)  carve((size_t)EE * 4);         //  4.0 MB
    int*   part = (int*)  carve((size_t)SCAN_NB * 4);
    int*   ppref= (int*)  carve((size_t)SCAN_NB * 4);

    hipMemsetAsync(deg, 0, (size_t)NN * 4, stream);

    pe_kernel<<<(NN * 16 + 255) / 256, 256, 0, stream>>>(rw, W_rwse, b_rwse, pe);
    inproj_kernel<<<NN / 32, 256, 0, stream>>>(x, pe, W_in, b_in, h);
    deg_kernel<<<(EE + 255) / 256, 256, 0, stream>>>(ei + EE, deg);
    scan1_kernel<<<SCAN_NB, 1024, 0, stream>>>(deg, part);
    scan2_kernel<<<1, 128, 0, stream>>>(part, ppref);
    scan3_kernel<<<SCAN_NB, 1024, 0, stream>>>(deg, ppref, offs, curs);
    fill_kernel<<<(EE + 255) / 256, 256, 0, stream>>>(ei, curs, ebuf);

    for (int l = 0; l < 2; ++l){
        gemm4_kernel<<<NN / 32, 256, 0, stream>>>(h,
            Wq + (size_t)l * 16384, bq + l * 128,
            Wk + (size_t)l * 16384, bk + l * 128,
            Wv + (size_t)l * 16384, bv + l * 128,
            Wsk + (size_t)l * 16384, bsk + l * 128,
            qb, kb, vf, sf);
        attn_kernel<<<NN / 4, 256, 0, stream>>>(h, qb, kb, vf, sf,
            offs, deg, ebuf, ln_g + l * 128, ln_b + l * 128);
    }
    pair_kernel<<<NPAIRSC / 16, 256, 0, stream>>>(h, src, dst, out);
}

// Round 3
// 596.046 us; speedup vs baseline: 1.9990x; 1.5838x over previous
//
#include <hip/hip_runtime.h>
#include <hip/hip_bf16.h>
#include <cstdint>

// GraphTransformerLinkPredictor on MI355X.
// pe proj -> fused input proj (fp32 h + bf16 hb) -> CSR build -> 2x {
//   gemm4 MFMA bf16 (q,k,v,skip all bf16 out) -> fused edge attn+LN (updates
//   h fp32 + hb bf16) } -> pair dot (fp32 h).
// Softmax identity: alpha = exp(s)/sum(exp(s)) (scores bounded, no max pass).

#define NN      100000
#define EE      1000000
#define RWSEC   16
#define WALKC   16
#define NPAIRSC 200000
#define SCAN_NB ((NN + 1023) / 1024)   // 98

typedef unsigned int       u32;
typedef unsigned short     u16;
typedef __attribute__((ext_vector_type(8))) short   short8;
typedef __attribute__((ext_vector_type(4))) float   f32x4;

__device__ __forceinline__ float bflo(u32 u){ return __uint_as_float(u << 16); }
__device__ __forceinline__ float bfhi(u32 u){ return __uint_as_float(u & 0xffff0000u); }
__device__ __forceinline__ u16 f2bf(float f){
    u32 u = __float_as_uint(f);
    u += 0x7fffu + ((u >> 16) & 1u);   // round-to-nearest-even
    return (u16)(u >> 16);
}
__device__ __forceinline__ u32 pack2(float a, float b){
    return (u32)f2bf(a) | ((u32)f2bf(b) << 16);
}

// ---------------- RWSE projection: pe[N,16] = rw[N,16] @ W[16,16] + b ----------------
__global__ __launch_bounds__(256) void pe_kernel(const float* __restrict__ rw,
                                                 const float* __restrict__ Wr,
                                                 const float* __restrict__ br,
                                                 float* __restrict__ pe){
    int idx = blockIdx.x * 256 + threadIdx.x;
    if (idx >= NN * RWSEC) return;
    int n = idx >> 4, j = idx & 15;
    const float* r = rw + (size_t)n * WALKC;
    float s = br[j];
    #pragma unroll
    for (int w = 0; w < WALKC; ++w) s = fmaf(r[w], Wr[w * RWSEC + j], s);
    pe[idx] = s;
}

// ---------------- input proj: h[N,128] = concat(x,pe)[N,144] @ W_in + b_in ----------------
__global__ __launch_bounds__(256) void inproj_kernel(const float* __restrict__ x,
                                                     const float* __restrict__ pe,
                                                     const float* __restrict__ Win,
                                                     const float* __restrict__ bin,
                                                     float* __restrict__ h,
                                                     u16* __restrict__ hb){
    __shared__ float xs[32 * 144];
    int tid = threadIdx.x;
    int n0  = blockIdx.x * 32;
    #pragma unroll
    for (int k = 0; k < 16; ++k){
        int idx = tid + k * 256;
        int n = idx >> 7, i = idx & 127;
        xs[n * 144 + i] = x[(size_t)(n0 + n) * 128 + i];
    }
    #pragma unroll
    for (int k = 0; k < 2; ++k){
        int id = tid + k * 256;
        int n = id >> 4, j = id & 15;
        xs[n * 144 + 128 + j] = pe[(size_t)(n0 + n) * 16 + j];
    }
    __syncthreads();
    int c = tid & 127, ng = tid >> 7;
    float acc[16];
    #pragma unroll
    for (int n = 0; n < 16; ++n) acc[n] = 0.f;
    for (int i4 = 0; i4 < 36; ++i4){
        int i = i4 * 4;
        float w0 = Win[(i + 0) * 128 + c];
        float w1 = Win[(i + 1) * 128 + c];
        float w2 = Win[(i + 2) * 128 + c];
        float w3 = Win[(i + 3) * 128 + c];
        #pragma unroll
        for (int n = 0; n < 16; ++n){
            const float4 hv = *reinterpret_cast<const float4*>(&xs[(ng * 16 + n) * 144 + i]);
            acc[n] = fmaf(hv.x, w0, fmaf(hv.y, w1, fmaf(hv.z, w2, fmaf(hv.w, w3, acc[n]))));
        }
    }
    float bb = bin[c];
    #pragma unroll
    for (int n = 0; n < 16; ++n){
        float v = acc[n] + bb;
        size_t p = (size_t)(n0 + ng * 16 + n) * 128 + c;
        h[p]  = v;
        hb[p] = f2bf(v);
    }
}

// ---------------- CSR build over col ----------------
__global__ __launch_bounds__(256) void deg_kernel(const int* __restrict__ col,
                                                  int* __restrict__ deg){
    int e = blockIdx.x * 256 + threadIdx.x;
    if (e < EE) atomicAdd(&deg[col[e]], 1);
}

__global__ __launch_bounds__(1024) void scan1_kernel(const int* __restrict__ deg,
                                                     int* __restrict__ partial){
    __shared__ int lds[16];
    int tid = threadIdx.x;
    int i = blockIdx.x * 1024 + tid;
    int v = (i < NN) ? deg[i] : 0;
    #pragma unroll
    for (int m = 1; m < 64; m <<= 1) v += __shfl_xor(v, m);
    if ((tid & 63) == 0) lds[tid >> 6] = v;
    __syncthreads();
    if (tid < 16){
        int s = lds[tid];
        #pragma unroll
        for (int m = 1; m < 16; m <<= 1) s += __shfl_xor(s, m, 16);
        if (tid == 0) partial[blockIdx.x] = s;
    }
}

__global__ __launch_bounds__(128) void scan2_kernel(const int* __restrict__ partial,
                                                    int* __restrict__ ppref){
    __shared__ int lds[128];
    int tid = threadIdx.x;
    int v = (tid < SCAN_NB) ? partial[tid] : 0;
    lds[tid] = v;
    __syncthreads();
    for (int off = 1; off < 128; off <<= 1){
        int y = (tid >= off) ? lds[tid - off] : 0;
        __syncthreads();
        lds[tid] += y;
        __syncthreads();
    }
    if (tid < SCAN_NB) ppref[tid] = lds[tid] - v;
}

__global__ __launch_bounds__(1024) void scan3_kernel(const int* __restrict__ deg,
                                                     const int* __restrict__ ppref,
                                                     int* __restrict__ offs,
                                                     int* __restrict__ cursor){
    __shared__ int wsum[16];
    int tid = threadIdx.x, lane = tid & 63, wid = tid >> 6;
    int i = blockIdx.x * 1024 + tid;
    int v = (i < NN) ? deg[i] : 0;
    int x = v;
    #pragma unroll
    for (int off = 1; off < 64; off <<= 1){
        int y = __shfl_up(x, off);
        if (lane >= off) x += y;
    }
    if (lane == 63) wsum[wid] = x;
    __syncthreads();
    if (tid < 16){
        int s = wsum[tid];
        int t = s;
        #pragma unroll
        for (int off = 1; off < 16; off <<= 1){
            int y = __shfl_up(t, off, 16);
            if (tid >= off) t += y;
        }
        wsum[tid] = t - s;
    }
    __syncthreads();
    int base = ppref[blockIdx.x] + wsum[wid] + (x - v);
    if (i < NN){ offs[i] = base; cursor[i] = base; }
}

__global__ __launch_bounds__(256) void fill_kernel(const int* __restrict__ ei,
                                                   int* __restrict__ cursor,
                                                   int* __restrict__ ebuf){
    int e = blockIdx.x * 256 + threadIdx.x;
    if (e < EE){
        int c = ei[EE + e];
        int p = atomicAdd(&cursor[c], 1);
        ebuf[p] = ei[e];
    }
}

// ---------------- weight prep: per-lane MFMA fragment layout, bf16 ----------------
// Wb2[layer][frag(gnt*4+kk)][lane][e] = bf16(W_m[k][col]),
//   gnt=0..31 (matrix m=gnt>>3), col=(gnt*16+(lane&15))&127, k=kk*32+(lane>>4)*8+e
__global__ __launch_bounds__(256) void wprep_kernel(const float* __restrict__ Wq,
        const float* __restrict__ Wk, const float* __restrict__ Wv,
        const float* __restrict__ Ws, u16* __restrict__ Wb2){
    int t = blockIdx.x * 256 + threadIdx.x;
    if (t >= 2 * 128 * 64) return;
    int lane = t & 63, fi = (t >> 6) & 127, l = t >> 13;
    int gnt = fi >> 2, kk = fi & 3;
    int m = gnt >> 3;
    int col = (gnt * 16 + (lane & 15)) & 127;
    const float* W = (m == 0 ? Wq : m == 1 ? Wk : m == 2 ? Wv : Ws) + (size_t)l * 16384;
    int k0 = kk * 32 + (lane >> 4) * 8;
    u16* dst = Wb2 + ((size_t)l * 128 + fi) * 512 + lane * 8;
    #pragma unroll
    for (int e = 0; e < 8; ++e) dst[e] = f2bf(W[(size_t)(k0 + e) * 128 + col]);
}

// ---------------- fused 4-matrix MFMA GEMM: out = h @ {Wq,Wk,Wv,Ws} + bias (bf16) ----------------
// block: 64 rows x 512 cols; wave w owns matrix w. D = mfma(Wfrag, hfrag) gives
// lane l: C[row=rg*16+(l&15)][ncol=nt*16+(l>>4)*4+j] -> 4 consecutive cols/lane.
__global__ __launch_bounds__(256) void gemm4_mfma(const u16* __restrict__ hb,
        const u16* __restrict__ Wb2,
        const float* __restrict__ bq, const float* __restrict__ bk,
        const float* __restrict__ bv, const float* __restrict__ bs,
        u16* __restrict__ qb, u16* __restrict__ kb,
        u16* __restrict__ vb, u16* __restrict__ sb){
    __shared__ u16 hs[64 * 128];        // 16 KB, XOR-swizzled rows of 256B
    __shared__ u16 ob[4][64 * 128];     // 64 KB, per-wave repack buffers
    int tid = threadIdx.x;
    int n0  = blockIdx.x * 64;
    // stage hb tile -> LDS (reg-staged so we can swizzle; rule 21)
    #pragma unroll
    for (int i = 0; i < 4; ++i){
        int c = i * 256 + tid;
        int row = c >> 4, cb = (c & 15) * 16;
        uint4 v = make_uint4(0u, 0u, 0u, 0u);
        if (n0 + row < NN)
            v = *reinterpret_cast<const uint4*>(hb + (size_t)(n0 + row) * 128 + cb / 2);
        *reinterpret_cast<uint4*>((char*)hs + row * 256 + (cb ^ ((row & 7) << 4))) = v;
    }
    __syncthreads();
    int l = tid & 63, w = tid >> 6;
    int r16 = l & 15, kq = l >> 4;
    // h fragments: whole K=128 for 64 rows, register-resident (16 x b128)
    short8 ha[4][4];
    #pragma unroll
    for (int rg = 0; rg < 4; ++rg)
        #pragma unroll
        for (int kk = 0; kk < 4; ++kk){
            int row = rg * 16 + r16;
            int byt = (kk * 64 + kq * 16) ^ ((row & 7) << 4);
            ha[rg][kk] = *reinterpret_cast<const short8*>((const char*)hs + row * 256 + byt);
        }
    const float* bp  = w == 0 ? bq : w == 1 ? bk : w == 2 ? bv : bs;
    u16*        outp = w == 0 ? qb : w == 1 ? kb : w == 2 ? vb : sb;
    const short8* wfrag = reinterpret_cast<const short8*>(Wb2) + (size_t)(w * 8) * 4 * 64;
    u16* myob = &ob[w][0];
    #pragma unroll
    for (int nt = 0; nt < 8; ++nt){
        f32x4 acc[4];
        #pragma unroll
        for (int rg = 0; rg < 4; ++rg) acc[rg] = (f32x4){0.f, 0.f, 0.f, 0.f};
        #pragma unroll
        for (int kk = 0; kk < 4; ++kk){
            short8 wf = wfrag[(nt * 4 + kk) * 64 + l];
            #pragma unroll
            for (int rg = 0; rg < 4; ++rg)
                acc[rg] = __builtin_amdgcn_mfma_f32_16x16x32_bf16(wf, ha[rg][kk], acc[rg], 0, 0, 0);
        }
        float4 bvv = *reinterpret_cast<const float4*>(bp + nt * 16 + kq * 4);
        #pragma unroll
        for (int rg = 0; rg < 4; ++rg){
            u32 p0 = pack2(acc[rg][0] + bvv.x, acc[rg][1] + bvv.y);
            u32 p1 = pack2(acc[rg][2] + bvv.z, acc[rg][3] + bvv.w);
            int row = rg * 16 + r16;
            int cb  = (nt * 32 + kq * 8) ^ ((row & 7) << 4);
            *reinterpret_cast<uint2*>((char*)myob + row * 256 + cb) = make_uint2(p0, p1);
        }
    }
    asm volatile("s_waitcnt lgkmcnt(0)" ::: "memory");
    // coalesced store: 16 lanes cover one 256B row segment per iteration
    #pragma unroll
    for (int i = 0; i < 16; ++i){
        int row = i * 4 + kq;
        int cb  = r16 * 16;
        uint4 v = *reinterpret_cast<const uint4*>((char*)myob + row * 256 + (cb ^ ((row & 7) << 4)));
        if (n0 + row < NN)
            *reinterpret_cast<uint4*>(outp + (size_t)(n0 + row) * 128 + cb / 2) = v;
    }
}

// ---------------- fused edge attention + aggregate + skip + residual + LN + ReLU ----------------
__global__ __launch_bounds__(256) void attn_kernel(float* __restrict__ h,
        u16* __restrict__ hbo,
        const u16* __restrict__ qb, const u16* __restrict__ kb,
        const u16* __restrict__ vb, const u16* __restrict__ sb,
        const int* __restrict__ offs, const int* __restrict__ deg,
        const int* __restrict__ ebuf,
        const float* __restrict__ g, const float* __restrict__ bta){
    int tid  = threadIdx.x;
    int lane = tid & 63;
    int n    = blockIdx.x * 4 + (tid >> 6);
    const u32 qu = *reinterpret_cast<const u32*>(qb + (size_t)n * 128 + lane * 2);
    float q0 = bflo(qu), q1 = bfhi(qu);
    int beg = offs[n], cnt = deg[n];
    float z = 0.f, a0 = 0.f, a1 = 0.f;
    const float scale = 0.17677669529663687f;   // 1/sqrt(32)
    for (int t = 0; t < cnt; ++t){
        int r = ebuf[beg + t];
        u32 ku = *reinterpret_cast<const u32*>(kb + (size_t)r * 128 + lane * 2);
        float s = q0 * bflo(ku) + q1 * bfhi(ku);
        s += __shfl_xor(s, 1); s += __shfl_xor(s, 2);
        s += __shfl_xor(s, 4); s += __shfl_xor(s, 8);
        float ex = __expf(s * scale);
        u32 vu = *reinterpret_cast<const u32*>(vb + (size_t)r * 128 + lane * 2);
        z += ex;
        a0 = fmaf(ex, bflo(vu), a0);
        a1 = fmaf(ex, bfhi(vu), a1);
    }
    float rz = (cnt > 0) ? 1.f / z : 0.f;
    size_t p0 = (size_t)n * 128 + lane * 2;
    u32 su = *reinterpret_cast<const u32*>(sb + p0);
    float y0 = h[p0]     + a0 * rz + bflo(su);
    float y1 = h[p0 + 1] + a1 * rz + bfhi(su);
    float sum = y0 + y1, sq = y0 * y0 + y1 * y1;
    #pragma unroll
    for (int m = 1; m < 64; m <<= 1){
        sum += __shfl_xor(sum, m);
        sq  += __shfl_xor(sq,  m);
    }
    float mu  = sum * (1.f / 128.f);
    float var = sq * (1.f / 128.f) - mu * mu;
    var = var < 0.f ? 0.f : var;
    float inv = rsqrtf(var + 1e-5f);
    int c = lane * 2;
    float o0 = fmaf(g[c]     * (y0 - mu), inv, bta[c]);
    float o1 = fmaf(g[c + 1] * (y1 - mu), inv, bta[c + 1]);
    o0 = o0 > 0.f ? o0 : 0.f;
    o1 = o1 > 0.f ? o1 : 0.f;
    h[p0]     = o0;
    h[p0 + 1] = o1;
    *reinterpret_cast<u32*>(hbo + p0) = pack2(o0, o1);
}

// ---------------- link prediction: sigmoid(h[src] . h[dst]) ----------------
__global__ __launch_bounds__(256) void pair_kernel(const float* __restrict__ h,
                                                   const int* __restrict__ src,
                                                   const int* __restrict__ dst,
                                                   float* __restrict__ out){
    int tid = threadIdx.x;
    int pid = blockIdx.x * 16 + (tid >> 4);
    int sub = tid & 15;
    int s = src[pid], d = dst[pid];
    const float4* A = reinterpret_cast<const float4*>(h + (size_t)s * 128 + sub * 8);
    const float4* B = reinterpret_cast<const float4*>(h + (size_t)d * 128 + sub * 8);
    float4 a0 = A[0], a1 = A[1], b0 = B[0], b1 = B[1];
    float dot = a0.x * b0.x + a0.y * b0.y + a0.z * b0.z + a0.w * b0.w
              + a1.x * b1.x + a1.y * b1.y + a1.z * b1.z + a1.w * b1.w;
    dot += __shfl_xor(dot, 1); dot += __shfl_xor(dot, 2);
    dot += __shfl_xor(dot, 4); dot += __shfl_xor(dot, 8);
    if (sub == 0) out[pid] = 1.f / (1.f + __expf(-dot));
}

extern "C" void kernel_launch(void* const* d_in, const int* in_sizes, int n_in,
                              void* d_out, int out_size, void* d_ws, size_t ws_size,
                              hipStream_t stream){
    const float* x      = (const float*)d_in[0];
    const float* rw     = (const float*)d_in[1];
    const int*   ei     = (const int*)  d_in[2];
    const int*   src    = (const int*)  d_in[3];
    const int*   dst    = (const int*)  d_in[4];
    const float* W_rwse = (const float*)d_in[5];
    const float* b_rwse = (const float*)d_in[6];
    const float* W_in   = (const float*)d_in[7];
    const float* b_in   = (const float*)d_in[8];
    const float* Wq     = (const float*)d_in[9];
    const float* bq     = (const float*)d_in[10];
    const float* Wk     = (const float*)d_in[11];
    const float* bk     = (const float*)d_in[12];
    const float* Wv     = (const float*)d_in[13];
    const float* bv     = (const float*)d_in[14];
    const float* Wsk    = (const float*)d_in[15];
    const float* bsk    = (const float*)d_in[16];
    const float* ln_g   = (const float*)d_in[17];
    const float* ln_b   = (const float*)d_in[18];
    float* out = (float*)d_out;

    char* p = (char*)d_ws;
    auto carve = [&](size_t bytes) -> char* {
        char* r = p; p += (bytes + 255) & ~(size_t)255; return r;
    };
    float* h    = (float*)carve((size_t)NN * 128 * 4);   // 51.2 MB
    u16*   hb   = (u16*)  carve((size_t)NN * 128 * 2);   // 25.6 MB
    float* pe   = (float*)carve((size_t)NN * 16 * 4);    //  6.4 MB
    u16*   qb   = (u16*)  carve((size_t)NN * 128 * 2);
    u16*   kb   = (u16*)  carve((size_t)NN * 128 * 2);
    u16*   vb   = (u16*)  carve((size_t)NN * 128 * 2);
    u16*   sb   = (u16*)  carve((size_t)NN * 128 * 2);
    int*   deg  = (int*)  carve((size_t)NN * 4);
    int*   offs = (int*)  carve((size_t)NN * 4);
    int*   curs = (int*)  carve((size_t)NN * 4);
    int*   ebuf = (int*)  carve((size_t)EE * 4);
    int*   part = (int*)  carve((size_t)SCAN_NB * 4);
    int*   ppref= (int*)  carve((size_t)SCAN_NB * 4);
    u16*   Wb2  = (u16*)  carve((size_t)2 * 128 * 512 * 2);  // 256 KB

    hipMemsetAsync(deg, 0, (size_t)NN * 4, stream);

    pe_kernel<<<(NN * 16 + 255) / 256, 256, 0, stream>>>(rw, W_rwse, b_rwse, pe);
    inproj_kernel<<<NN / 32, 256, 0, stream>>>(x, pe, W_in, b_in, h, hb);
    wprep_kernel<<<64, 256, 0, stream>>>(Wq, Wk, Wv, Wsk, Wb2);
    deg_kernel<<<(EE + 255) / 256, 256, 0, stream>>>(ei + EE, deg);
    scan1_kernel<<<SCAN_NB, 1024, 0, stream>>>(deg, part);
    scan2_kernel<<<1, 128, 0, stream>>>(part, ppref);
    scan3_kernel<<<SCAN_NB, 1024, 0, stream>>>(deg, ppref, offs, curs);
    fill_kernel<<<(EE + 255) / 256, 256, 0, stream>>>(ei, curs, ebuf);

    for (int l = 0; l < 2; ++l){
        gemm4_mfma<<<(NN + 63) / 64, 256, 0, stream>>>(hb, Wb2 + (size_t)l * 65536,
            bq + l * 128, bk + l * 128, bv + l * 128, bsk + l * 128,
            qb, kb, vb, sb);
        attn_kernel<<<NN / 4, 256, 0, stream>>>(h, hb, qb, kb, vb, sb,
            offs, deg, ebuf, ln_g + l * 128, ln_b + l * 128);
    }
    pair_kernel<<<NPAIRSC / 16, 256, 0, stream>>>(h, src, dst, out);
}

// Round 4
// 475.556 us; speedup vs baseline: 2.5055x; 1.2534x over previous
//
#include <hip/hip_runtime.h>
#include <hip/hip_bf16.h>
#include <cstdint>

// GraphTransformerLinkPredictor on MI355X.
// bf16-canonical h. pe proj -> fused input proj (bf16 hb) -> CSR build -> 2x {
//   gemm4 MFMA bf16 -> fused edge attn+LN (dual-edge half-wave, 4 edges in
//   flight) } -> pair dot (bf16).
// Softmax identity: alpha = exp(s)/sum(exp(s)) (scores bounded, no max pass).

#define NN      100000
#define EE      1000000
#define RWSEC   16
#define WALKC   16
#define NPAIRSC 200000
#define SCAN_NB ((NN + 1023) / 1024)   // 98

typedef unsigned int       u32;
typedef unsigned short     u16;
typedef __attribute__((ext_vector_type(8))) short   short8;
typedef __attribute__((ext_vector_type(4))) float   f32x4;

__device__ __forceinline__ float bflo(u32 u){ return __uint_as_float(u << 16); }
__device__ __forceinline__ float bfhi(u32 u){ return __uint_as_float(u & 0xffff0000u); }
__device__ __forceinline__ u16 f2bf(float f){
    u32 u = __float_as_uint(f);
    u += 0x7fffu + ((u >> 16) & 1u);   // round-to-nearest-even
    return (u16)(u >> 16);
}
__device__ __forceinline__ u32 pack2(float a, float b){
    return (u32)f2bf(a) | ((u32)f2bf(b) << 16);
}

// ---------------- RWSE projection: pe[N,16] = rw[N,16] @ W[16,16] + b ----------------
__global__ __launch_bounds__(256) void pe_kernel(const float* __restrict__ rw,
                                                 const float* __restrict__ Wr,
                                                 const float* __restrict__ br,
                                                 float* __restrict__ pe){
    int idx = blockIdx.x * 256 + threadIdx.x;
    if (idx >= NN * RWSEC) return;
    int n = idx >> 4, j = idx & 15;
    const float* r = rw + (size_t)n * WALKC;
    float s = br[j];
    #pragma unroll
    for (int w = 0; w < WALKC; ++w) s = fmaf(r[w], Wr[w * RWSEC + j], s);
    pe[idx] = s;
}

// ---------------- input proj: hb[N,128] = bf16(concat(x,pe)[N,144] @ W_in + b_in) ----------------
__global__ __launch_bounds__(256) void inproj_kernel(const float* __restrict__ x,
                                                     const float* __restrict__ pe,
                                                     const float* __restrict__ Win,
                                                     const float* __restrict__ bin,
                                                     u16* __restrict__ hb){
    __shared__ float xs[32 * 144];
    int tid = threadIdx.x;
    int n0  = blockIdx.x * 32;
    #pragma unroll
    for (int k = 0; k < 16; ++k){
        int idx = tid + k * 256;
        int n = idx >> 7, i = idx & 127;
        xs[n * 144 + i] = x[(size_t)(n0 + n) * 128 + i];
    }
    #pragma unroll
    for (int k = 0; k < 2; ++k){
        int id = tid + k * 256;
        int n = id >> 4, j = id & 15;
        xs[n * 144 + 128 + j] = pe[(size_t)(n0 + n) * 16 + j];
    }
    __syncthreads();
    int c = tid & 127, ng = tid >> 7;
    float acc[16];
    #pragma unroll
    for (int n = 0; n < 16; ++n) acc[n] = 0.f;
    for (int i4 = 0; i4 < 36; ++i4){
        int i = i4 * 4;
        float w0 = Win[(i + 0) * 128 + c];
        float w1 = Win[(i + 1) * 128 + c];
        float w2 = Win[(i + 2) * 128 + c];
        float w3 = Win[(i + 3) * 128 + c];
        #pragma unroll
        for (int n = 0; n < 16; ++n){
            const float4 hv = *reinterpret_cast<const float4*>(&xs[(ng * 16 + n) * 144 + i]);
            acc[n] = fmaf(hv.x, w0, fmaf(hv.y, w1, fmaf(hv.z, w2, fmaf(hv.w, w3, acc[n]))));
        }
    }
    float bb = bin[c];
    #pragma unroll
    for (int n = 0; n < 16; ++n)
        hb[(size_t)(n0 + ng * 16 + n) * 128 + c] = f2bf(acc[n] + bb);
}

// ---------------- CSR build over col ----------------
__global__ __launch_bounds__(256) void deg_kernel(const int* __restrict__ col,
                                                  int* __restrict__ deg){
    int e = blockIdx.x * 256 + threadIdx.x;
    if (e < EE) atomicAdd(&deg[col[e]], 1);
}

__global__ __launch_bounds__(1024) void scan1_kernel(const int* __restrict__ deg,
                                                     int* __restrict__ partial){
    __shared__ int lds[16];
    int tid = threadIdx.x;
    int i = blockIdx.x * 1024 + tid;
    int v = (i < NN) ? deg[i] : 0;
    #pragma unroll
    for (int m = 1; m < 64; m <<= 1) v += __shfl_xor(v, m);
    if ((tid & 63) == 0) lds[tid >> 6] = v;
    __syncthreads();
    if (tid < 16){
        int s = lds[tid];
        #pragma unroll
        for (int m = 1; m < 16; m <<= 1) s += __shfl_xor(s, m, 16);
        if (tid == 0) partial[blockIdx.x] = s;
    }
}

__global__ __launch_bounds__(128) void scan2_kernel(const int* __restrict__ partial,
                                                    int* __restrict__ ppref){
    __shared__ int lds[128];
    int tid = threadIdx.x;
    int v = (tid < SCAN_NB) ? partial[tid] : 0;
    lds[tid] = v;
    __syncthreads();
    for (int off = 1; off < 128; off <<= 1){
        int y = (tid >= off) ? lds[tid - off] : 0;
        __syncthreads();
        lds[tid] += y;
        __syncthreads();
    }
    if (tid < SCAN_NB) ppref[tid] = lds[tid] - v;
}

__global__ __launch_bounds__(1024) void scan3_kernel(const int* __restrict__ deg,
                                                     const int* __restrict__ ppref,
                                                     int* __restrict__ offs,
                                                     int* __restrict__ cursor){
    __shared__ int wsum[16];
    int tid = threadIdx.x, lane = tid & 63, wid = tid >> 6;
    int i = blockIdx.x * 1024 + tid;
    int v = (i < NN) ? deg[i] : 0;
    int x = v;
    #pragma unroll
    for (int off = 1; off < 64; off <<= 1){
        int y = __shfl_up(x, off);
        if (lane >= off) x += y;
    }
    if (lane == 63) wsum[wid] = x;
    __syncthreads();
    if (tid < 16){
        int s = wsum[tid];
        int t = s;
        #pragma unroll
        for (int off = 1; off < 16; off <<= 1){
            int y = __shfl_up(t, off, 16);
            if (tid >= off) t += y;
        }
        wsum[tid] = t - s;
    }
    __syncthreads();
    int base = ppref[blockIdx.x] + wsum[wid] + (x - v);
    if (i < NN){ offs[i] = base; cursor[i] = base; }
}

__global__ __launch_bounds__(256) void fill_kernel(const int* __restrict__ ei,
                                                   int* __restrict__ cursor,
                                                   int* __restrict__ ebuf){
    int e = blockIdx.x * 256 + threadIdx.x;
    if (e < EE){
        int c = ei[EE + e];
        int p = atomicAdd(&cursor[c], 1);
        ebuf[p] = ei[e];
    }
}

// ---------------- weight prep: per-lane MFMA fragment layout, bf16 ----------------
__global__ __launch_bounds__(256) void wprep_kernel(const float* __restrict__ Wq,
        const float* __restrict__ Wk, const float* __restrict__ Wv,
        const float* __restrict__ Ws, u16* __restrict__ Wb2){
    int t = blockIdx.x * 256 + threadIdx.x;
    if (t >= 2 * 128 * 64) return;
    int lane = t & 63, fi = (t >> 6) & 127, l = t >> 13;
    int gnt = fi >> 2, kk = fi & 3;
    int m = gnt >> 3;
    int col = (gnt * 16 + (lane & 15)) & 127;
    const float* W = (m == 0 ? Wq : m == 1 ? Wk : m == 2 ? Wv : Ws) + (size_t)l * 16384;
    int k0 = kk * 32 + (lane >> 4) * 8;
    u16* dst = Wb2 + ((size_t)l * 128 + fi) * 512 + lane * 8;
    #pragma unroll
    for (int e = 0; e < 8; ++e) dst[e] = f2bf(W[(size_t)(k0 + e) * 128 + col]);
}

// ---------------- fused 4-matrix MFMA GEMM: out = h @ {Wq,Wk,Wv,Ws} + bias (bf16) ----------------
__global__ __launch_bounds__(256) void gemm4_mfma(const u16* __restrict__ hb,
        const u16* __restrict__ Wb2,
        const float* __restrict__ bq, const float* __restrict__ bk,
        const float* __restrict__ bv, const float* __restrict__ bs,
        u16* __restrict__ qb, u16* __restrict__ kb,
        u16* __restrict__ vb, u16* __restrict__ sb){
    __shared__ u16 hs[64 * 128];        // 16 KB, XOR-swizzled rows of 256B
    __shared__ u16 ob[4][64 * 128];     // 64 KB, per-wave repack buffers
    int tid = threadIdx.x;
    int n0  = blockIdx.x * 64;
    #pragma unroll
    for (int i = 0; i < 4; ++i){
        int c = i * 256 + tid;
        int row = c >> 4, cb = (c & 15) * 16;
        uint4 v = make_uint4(0u, 0u, 0u, 0u);
        if (n0 + row < NN)
            v = *reinterpret_cast<const uint4*>(hb + (size_t)(n0 + row) * 128 + cb / 2);
        *reinterpret_cast<uint4*>((char*)hs + row * 256 + (cb ^ ((row & 7) << 4))) = v;
    }
    __syncthreads();
    int l = tid & 63, w = tid >> 6;
    int r16 = l & 15, kq = l >> 4;
    short8 ha[4][4];
    #pragma unroll
    for (int rg = 0; rg < 4; ++rg)
        #pragma unroll
        for (int kk = 0; kk < 4; ++kk){
            int row = rg * 16 + r16;
            int byt = (kk * 64 + kq * 16) ^ ((row & 7) << 4);
            ha[rg][kk] = *reinterpret_cast<const short8*>((const char*)hs + row * 256 + byt);
        }
    const float* bp  = w == 0 ? bq : w == 1 ? bk : w == 2 ? bv : bs;
    u16*        outp = w == 0 ? qb : w == 1 ? kb : w == 2 ? vb : sb;
    const short8* wfrag = reinterpret_cast<const short8*>(Wb2) + (size_t)(w * 8) * 4 * 64;
    u16* myob = &ob[w][0];
    #pragma unroll
    for (int nt = 0; nt < 8; ++nt){
        f32x4 acc[4];
        #pragma unroll
        for (int rg = 0; rg < 4; ++rg) acc[rg] = (f32x4){0.f, 0.f, 0.f, 0.f};
        #pragma unroll
        for (int kk = 0; kk < 4; ++kk){
            short8 wf = wfrag[(nt * 4 + kk) * 64 + l];
            #pragma unroll
            for (int rg = 0; rg < 4; ++rg)
                acc[rg] = __builtin_amdgcn_mfma_f32_16x16x32_bf16(wf, ha[rg][kk], acc[rg], 0, 0, 0);
        }
        float4 bvv = *reinterpret_cast<const float4*>(bp + nt * 16 + kq * 4);
        #pragma unroll
        for (int rg = 0; rg < 4; ++rg){
            u32 p0 = pack2(acc[rg][0] + bvv.x, acc[rg][1] + bvv.y);
            u32 p1 = pack2(acc[rg][2] + bvv.z, acc[rg][3] + bvv.w);
            int row = rg * 16 + r16;
            int cb  = (nt * 32 + kq * 8) ^ ((row & 7) << 4);
            *reinterpret_cast<uint2*>((char*)myob + row * 256 + cb) = make_uint2(p0, p1);
        }
    }
    asm volatile("s_waitcnt lgkmcnt(0)" ::: "memory");
    #pragma unroll
    for (int i = 0; i < 16; ++i){
        int row = i * 4 + kq;
        int cb  = r16 * 16;
        uint4 v = *reinterpret_cast<const uint4*>((char*)myob + row * 256 + (cb ^ ((row & 7) << 4)));
        if (n0 + row < NN)
            *reinterpret_cast<uint4*>(outp + (size_t)(n0 + row) * 128 + cb / 2) = v;
    }
}

// ---------------- fused edge attention + aggregate + skip + residual + LN + ReLU ----------------
// 1 wave/node; lanes 0-31 = edge A, lanes 32-63 = edge B; 4 dims/lane (uint2).
// head = sl>>3 (8 lanes x 4 dims = 32 dims); z,acc combined across halves at end.
__global__ __launch_bounds__(256) void attn_kernel(u16* __restrict__ hb,
        const u16* __restrict__ qb, const u16* __restrict__ kb,
        const u16* __restrict__ vb, const u16* __restrict__ sb,
        const int* __restrict__ offs, const int* __restrict__ deg,
        const int* __restrict__ ebuf,
        const float* __restrict__ g, const float* __restrict__ bta){
    int tid  = threadIdx.x;
    int lane = tid & 63;
    int n    = blockIdx.x * 4 + (tid >> 6);
    int half = lane >> 5, sl = lane & 31;
    const uint2 qu = *reinterpret_cast<const uint2*>(qb + (size_t)n * 128 + sl * 4);
    float q0 = bflo(qu.x), q1 = bfhi(qu.x), q2 = bflo(qu.y), q3 = bfhi(qu.y);
    int beg = offs[n], cnt = deg[n];
    float z = 0.f, a0 = 0.f, a1 = 0.f, a2 = 0.f, a3 = 0.f;
    const float scale = 0.17677669529663687f;   // 1/sqrt(32)

    #define EDGE2(rA_, rB_)                                                         \
    {   int r_ = half ? (rB_) : (rA_);                                              \
        uint2 ku = *reinterpret_cast<const uint2*>(kb + (size_t)r_ * 128 + sl * 4); \
        uint2 vu = *reinterpret_cast<const uint2*>(vb + (size_t)r_ * 128 + sl * 4); \
        float s = q0 * bflo(ku.x) + q1 * bfhi(ku.x)                                 \
                + q2 * bflo(ku.y) + q3 * bfhi(ku.y);                                \
        s += __shfl_xor(s, 1); s += __shfl_xor(s, 2); s += __shfl_xor(s, 4);        \
        float ex = __expf(s * scale);                                               \
        z += ex;                                                                    \
        a0 = fmaf(ex, bflo(vu.x), a0); a1 = fmaf(ex, bfhi(vu.x), a1);               \
        a2 = fmaf(ex, bflo(vu.y), a2); a3 = fmaf(ex, bfhi(vu.y), a3);  }

    int t = 0;
    for (; t + 4 <= cnt; t += 4){            // 4 edges in flight
        int r0 = ebuf[beg + t],     r1 = ebuf[beg + t + 1];
        int r2 = ebuf[beg + t + 2], r3 = ebuf[beg + t + 3];
        EDGE2(r0, r1);
        EDGE2(r2, r3);
    }
    if (t + 2 <= cnt){
        int r0 = ebuf[beg + t], r1 = ebuf[beg + t + 1];
        EDGE2(r0, r1);
        t += 2;
    }
    if (t < cnt){                            // tail: half A only
        int r = ebuf[beg + t];
        uint2 ku = *reinterpret_cast<const uint2*>(kb + (size_t)r * 128 + sl * 4);
        uint2 vu = *reinterpret_cast<const uint2*>(vb + (size_t)r * 128 + sl * 4);
        float s = q0 * bflo(ku.x) + q1 * bfhi(ku.x)
                + q2 * bflo(ku.y) + q3 * bfhi(ku.y);
        s += __shfl_xor(s, 1); s += __shfl_xor(s, 2); s += __shfl_xor(s, 4);
        float ex = half ? 0.f : __expf(s * scale);
        z += ex;
        a0 = fmaf(ex, bflo(vu.x), a0); a1 = fmaf(ex, bfhi(vu.x), a1);
        a2 = fmaf(ex, bflo(vu.y), a2); a3 = fmaf(ex, bfhi(vu.y), a3);
    }
    #undef EDGE2

    z  += __shfl_xor(z, 32);
    a0 += __shfl_xor(a0, 32); a1 += __shfl_xor(a1, 32);
    a2 += __shfl_xor(a2, 32); a3 += __shfl_xor(a3, 32);
    float rz = (cnt > 0) ? 1.f / z : 0.f;

    size_t p = (size_t)n * 128 + sl * 4;
    uint2 hu = *reinterpret_cast<const uint2*>(hb + p);
    uint2 su = *reinterpret_cast<const uint2*>(sb + p);
    float y0 = bflo(hu.x) + a0 * rz + bflo(su.x);
    float y1 = bfhi(hu.x) + a1 * rz + bfhi(su.x);
    float y2 = bflo(hu.y) + a2 * rz + bflo(su.y);
    float y3 = bfhi(hu.y) + a3 * rz + bfhi(su.y);
    float sum = y0 + y1 + y2 + y3;
    float sq  = y0 * y0 + y1 * y1 + y2 * y2 + y3 * y3;
    #pragma unroll
    for (int m = 1; m < 32; m <<= 1){        // each half holds all 128 dims
        sum += __shfl_xor(sum, m);
        sq  += __shfl_xor(sq,  m);
    }
    float mu  = sum * (1.f / 128.f);
    float var = sq * (1.f / 128.f) - mu * mu;
    var = var < 0.f ? 0.f : var;
    float inv = rsqrtf(var + 1e-5f);
    int c = sl * 4;
    float o0 = fmaf(g[c    ] * (y0 - mu), inv, bta[c    ]);
    float o1 = fmaf(g[c + 1] * (y1 - mu), inv, bta[c + 1]);
    float o2 = fmaf(g[c + 2] * (y2 - mu), inv, bta[c + 2]);
    float o3 = fmaf(g[c + 3] * (y3 - mu), inv, bta[c + 3]);
    o0 = o0 > 0.f ? o0 : 0.f;  o1 = o1 > 0.f ? o1 : 0.f;
    o2 = o2 > 0.f ? o2 : 0.f;  o3 = o3 > 0.f ? o3 : 0.f;
    if (!half)
        *reinterpret_cast<uint2*>(hb + p) = make_uint2(pack2(o0, o1), pack2(o2, o3));
}

// ---------------- link prediction: sigmoid(h[src] . h[dst]) (bf16) ----------------
__global__ __launch_bounds__(256) void pair_kernel(const u16* __restrict__ hb,
                                                   const int* __restrict__ src,
                                                   const int* __restrict__ dst,
                                                   float* __restrict__ out){
    int tid = threadIdx.x;
    int pid = blockIdx.x * 16 + (tid >> 4);
    int sub = tid & 15;
    int s = src[pid], d = dst[pid];
    uint4 a = *reinterpret_cast<const uint4*>(hb + (size_t)s * 128 + sub * 8);
    uint4 b = *reinterpret_cast<const uint4*>(hb + (size_t)d * 128 + sub * 8);
    float dot = bflo(a.x) * bflo(b.x) + bfhi(a.x) * bfhi(b.x)
              + bflo(a.y) * bflo(b.y) + bfhi(a.y) * bfhi(b.y)
              + bflo(a.z) * bflo(b.z) + bfhi(a.z) * bfhi(b.z)
              + bflo(a.w) * bflo(b.w) + bfhi(a.w) * bfhi(b.w);
    dot += __shfl_xor(dot, 1); dot += __shfl_xor(dot, 2);
    dot += __shfl_xor(dot, 4); dot += __shfl_xor(dot, 8);
    if (sub == 0) out[pid] = 1.f / (1.f + __expf(-dot));
}

extern "C" void kernel_launch(void* const* d_in, const int* in_sizes, int n_in,
                              void* d_out, int out_size, void* d_ws, size_t ws_size,
                              hipStream_t stream){
    const float* x      = (const float*)d_in[0];
    const float* rw     = (const float*)d_in[1];
    const int*   ei     = (const int*)  d_in[2];
    const int*   src    = (const int*)  d_in[3];
    const int*   dst    = (const int*)  d_in[4];
    const float* W_rwse = (const float*)d_in[5];
    const float* b_rwse = (const float*)d_in[6];
    const float* W_in   = (const float*)d_in[7];
    const float* b_in   = (const float*)d_in[8];
    const float* Wq     = (const float*)d_in[9];
    const float* bq     = (const float*)d_in[10];
    const float* Wk     = (const float*)d_in[11];
    const float* bk     = (const float*)d_in[12];
    const float* Wv     = (const float*)d_in[13];
    const float* bv     = (const float*)d_in[14];
    const float* Wsk    = (const float*)d_in[15];
    const float* bsk    = (const float*)d_in[16];
    const float* ln_g   = (const float*)d_in[17];
    const float* ln_b   = (const float*)d_in[18];
    float* out = (float*)d_out;

    char* p = (char*)d_ws;
    auto carve = [&](size_t bytes) -> char* {
        char* r = p; p += (bytes + 255) & ~(size_t)255; return r;
    };
    u16*   hb   = (u16*)  carve((size_t)NN * 128 * 2);   // 25.6 MB
    float* pe   = (float*)carve((size_t)NN * 16 * 4);    //  6.4 MB
    u16*   qb   = (u16*)  carve((size_t)NN * 128 * 2);
    u16*   kb   = (u16*)  carve((size_t)NN * 128 * 2);
    u16*   vb   = (u16*)  carve((size_t)NN * 128 * 2);
    u16*   sb   = (u16*)  carve((size_t)NN * 128 * 2);
    int*   deg  = (int*)  carve((size_t)NN * 4);
    int*   offs = (int*)  carve((size_t)NN * 4);
    int*   curs = (int*)  carve((size_t)NN * 4);
    int*   ebuf = (int*)  carve((size_t)EE * 4);
    int*   part = (int*)  carve((size_t)SCAN_NB * 4);
    int*   ppref= (int*)  carve((size_t)SCAN_NB * 4);
    u16*   Wb2  = (u16*)  carve((size_t)2 * 128 * 512 * 2);  // 256 KB

    hipMemsetAsync(deg, 0, (size_t)NN * 4, stream);

    pe_kernel<<<(NN * 16 + 255) / 256, 256, 0, stream>>>(rw, W_rwse, b_rwse, pe);
    inproj_kernel<<<NN / 32, 256, 0, stream>>>(x, pe, W_in, b_in, hb);
    wprep_kernel<<<64, 256, 0, stream>>>(Wq, Wk, Wv, Wsk, Wb2);
    deg_kernel<<<(EE + 255) / 256, 256, 0, stream>>>(ei + EE, deg);
    scan1_kernel<<<SCAN_NB, 1024, 0, stream>>>(deg, part);
    scan2_kernel<<<1, 128, 0, stream>>>(part, ppref);
    scan3_kernel<<<SCAN_NB, 1024, 0, stream>>>(deg, ppref, offs, curs);
    fill_kernel<<<(EE + 255) / 256, 256, 0, stream>>>(ei, curs, ebuf);

    for (int l = 0; l < 2; ++l){
        gemm4_mfma<<<(NN + 63) / 64, 256, 0, stream>>>(hb, Wb2 + (size_t)l * 65536,
            bq + l * 128, bk + l * 128, bv + l * 128, bsk + l * 128,
            qb, kb, vb, sb);
        attn_kernel<<<NN / 4, 256, 0, stream>>>(hb, qb, kb, vb, sb,
            offs, deg, ebuf, ln_g + l * 128, ln_b + l * 128);
    }
    pair_kernel<<<NPAIRSC / 16, 256, 0, stream>>>(hb, src, dst, out);
}

// Round 5
// 435.844 us; speedup vs baseline: 2.7338x; 1.0911x over previous
//
#include <hip/hip_runtime.h>
#include <hip/hip_bf16.h>
#include <cstdint>

// GraphTransformerLinkPredictor on MI355X.
// bf16-canonical h. fused MFMA input proj (pe fused in, K=144 padded to 160)
// -> CSR build -> 2x { gemm4 MFMA bf16 -> fused edge attn+LN (dual-edge
// half-wave, 4 edges in flight) } -> pair dot (bf16).
// Softmax identity: alpha = exp(s)/sum(exp(s)) (scores bounded, no max pass).

#define NN      100000
#define EE      1000000
#define RWSEC   16
#define WALKC   16
#define NPAIRSC 200000
#define SCAN_NB ((NN + 1023) / 1024)   // 98

typedef unsigned int       u32;
typedef unsigned short     u16;
typedef __attribute__((ext_vector_type(8))) short   short8;
typedef __attribute__((ext_vector_type(4))) float   f32x4;

__device__ __forceinline__ float bflo(u32 u){ return __uint_as_float(u << 16); }
__device__ __forceinline__ float bfhi(u32 u){ return __uint_as_float(u & 0xffff0000u); }
__device__ __forceinline__ u16 f2bf(float f){
    u32 u = __float_as_uint(f);
    u += 0x7fffu + ((u >> 16) & 1u);   // round-to-nearest-even
    return (u16)(u >> 16);
}
__device__ __forceinline__ u32 pack2(float a, float b){
    return (u32)f2bf(a) | ((u32)f2bf(b) << 16);
}

// ---------------- W_in prep: per-lane MFMA fragments, K padded 144->160 ----------------
// Winb[(nt*5+kk)*64+lane][e] = bf16(W_in[k][col]); col=nt*16+(lane&15),
// k=kk*32+(lane>>4)*8+e, zero for k>=144.
__global__ __launch_bounds__(256) void winprep_kernel(const float* __restrict__ Win,
                                                      u16* __restrict__ Winb){
    int t = blockIdx.x * 256 + threadIdx.x;
    if (t >= 8 * 5 * 64) return;
    int lane = t & 63, fi = t >> 6;          // fi = nt*5+kk
    int nt = fi / 5, kk = fi - nt * 5;
    int col = nt * 16 + (lane & 15);
    int k0  = kk * 32 + (lane >> 4) * 8;
    u16* dst = Winb + (size_t)fi * 512 + lane * 8;
    #pragma unroll
    for (int e = 0; e < 8; ++e){
        int k = k0 + e;
        dst[e] = (k < 144) ? f2bf(Win[(size_t)k * 128 + col]) : (u16)0;
    }
}

// ---------------- fused input proj (MFMA): hb = bf16(concat(x, rw@Wr+br) @ W_in + b_in) ----------------
// 64 rows/block, 4 waves; wave w owns col-tiles nt=2w,2w+1. LDS h-tile row
// stride 336B (21x16B): natural bank stagger -> 2-way conflicts (free).
__global__ __launch_bounds__(256) void inproj_mfma(const float* __restrict__ x,
        const float* __restrict__ rw, const float* __restrict__ Wr,
        const float* __restrict__ br,
        const u16* __restrict__ Winb, const float* __restrict__ bin,
        u16* __restrict__ hb){
    __shared__ u16   hs[64 * 168];     // 21504 B, row stride 336 B, cols 0..159
    __shared__ float rws[64 * 16];     // 4 KB raw rw tile
    __shared__ u16   ob[64 * 128];     // 16 KB output repack (256B rows, XOR swz)
    int tid = threadIdx.x;
    int n0  = blockIdx.x * 64;

    // stage x (64x128 fp32 -> bf16) into hs
    #pragma unroll
    for (int i = 0; i < 32; ++i){
        int g   = i * 256 + tid;
        int row = g >> 5, c4 = g & 31;       // 32 float4 per row
        float4 f = make_float4(0.f, 0.f, 0.f, 0.f);
        if (n0 + row < NN)
            f = *reinterpret_cast<const float4*>(x + (size_t)(n0 + row) * 128 + c4 * 4);
        *reinterpret_cast<uint2*>((char*)hs + row * 336 + c4 * 8)
            = make_uint2(pack2(f.x, f.y), pack2(f.z, f.w));
    }
    // stage rw (64x16 fp32)
    {
        int row = tid >> 2, c4 = tid & 3;
        float4 f = make_float4(0.f, 0.f, 0.f, 0.f);
        if (n0 + row < NN)
            f = *reinterpret_cast<const float4*>(rw + (size_t)(n0 + row) * 16 + c4 * 4);
        *reinterpret_cast<float4*>(&rws[row * 16 + c4 * 4]) = f;
    }
    __syncthreads();
    // pe compute: thread t -> row t>>2, cols (t&3)*4..+3 of pe; write bf16 + zero-pad
    {
        int row = tid >> 2, j0 = (tid & 3) * 4;
        float p0 = br[j0], p1 = br[j0 + 1], p2 = br[j0 + 2], p3 = br[j0 + 3];
        #pragma unroll
        for (int w = 0; w < 16; ++w){
            float r = rws[row * 16 + w];
            const float4 wv = *reinterpret_cast<const float4*>(Wr + w * 16 + j0);
            p0 = fmaf(r, wv.x, p0); p1 = fmaf(r, wv.y, p1);
            p2 = fmaf(r, wv.z, p2); p3 = fmaf(r, wv.w, p3);
        }
        *reinterpret_cast<uint2*>((char*)hs + row * 336 + 256 + (tid & 3) * 8)
            = make_uint2(pack2(p0, p1), pack2(p2, p3));
        *reinterpret_cast<uint2*>((char*)hs + row * 336 + 288 + (tid & 3) * 8)
            = make_uint2(0u, 0u);            // zero pad cols 144..159
    }
    __syncthreads();

    int l = tid & 63, w = tid >> 6;
    int r16 = l & 15, kq = l >> 4;
    // h fragments: K=160 (5 k-tiles) for 64 rows
    short8 ha[4][5];
    #pragma unroll
    for (int rg = 0; rg < 4; ++rg)
        #pragma unroll
        for (int kk = 0; kk < 5; ++kk){
            int row = rg * 16 + r16;
            ha[rg][kk] = *reinterpret_cast<const short8*>(
                (const char*)hs + row * 336 + kk * 64 + kq * 16);
        }
    #pragma unroll
    for (int nt2 = 0; nt2 < 2; ++nt2){
        int nt = w * 2 + nt2;
        const short8* wfrag = reinterpret_cast<const short8*>(Winb) + (size_t)(nt * 5) * 64;
        f32x4 acc[4];
        #pragma unroll
        for (int rg = 0; rg < 4; ++rg) acc[rg] = (f32x4){0.f, 0.f, 0.f, 0.f};
        #pragma unroll
        for (int kk = 0; kk < 5; ++kk){
            short8 wf = wfrag[kk * 64 + l];
            #pragma unroll
            for (int rg = 0; rg < 4; ++rg)
                acc[rg] = __builtin_amdgcn_mfma_f32_16x16x32_bf16(wf, ha[rg][kk], acc[rg], 0, 0, 0);
        }
        float4 bvv = *reinterpret_cast<const float4*>(bin + nt * 16 + kq * 4);
        #pragma unroll
        for (int rg = 0; rg < 4; ++rg){
            u32 p0 = pack2(acc[rg][0] + bvv.x, acc[rg][1] + bvv.y);
            u32 p1 = pack2(acc[rg][2] + bvv.z, acc[rg][3] + bvv.w);
            int row = rg * 16 + r16;
            int cb  = (nt * 32 + kq * 8) ^ ((row & 7) << 4);
            *reinterpret_cast<uint2*>((char*)ob + row * 256 + cb) = make_uint2(p0, p1);
        }
    }
    __syncthreads();
    // coalesced store: 16 lanes x 16B cover one 256B row
    #pragma unroll
    for (int i = 0; i < 4; ++i){
        int row = i * 16 + (tid >> 4);
        int cb  = (tid & 15) * 16;
        uint4 v = *reinterpret_cast<const uint4*>(
            (char*)ob + row * 256 + (cb ^ ((row & 7) << 4)));
        if (n0 + row < NN)
            *reinterpret_cast<uint4*>(hb + (size_t)(n0 + row) * 128 + cb / 2) = v;
    }
}

// ---------------- CSR build over col ----------------
__global__ __launch_bounds__(256) void deg_kernel(const int* __restrict__ col,
                                                  int* __restrict__ deg){
    int e = blockIdx.x * 256 + threadIdx.x;
    if (e < EE) atomicAdd(&deg[col[e]], 1);
}

__global__ __launch_bounds__(1024) void scan1_kernel(const int* __restrict__ deg,
                                                     int* __restrict__ partial){
    __shared__ int lds[16];
    int tid = threadIdx.x;
    int i = blockIdx.x * 1024 + tid;
    int v = (i < NN) ? deg[i] : 0;
    #pragma unroll
    for (int m = 1; m < 64; m <<= 1) v += __shfl_xor(v, m);
    if ((tid & 63) == 0) lds[tid >> 6] = v;
    __syncthreads();
    if (tid < 16){
        int s = lds[tid];
        #pragma unroll
        for (int m = 1; m < 16; m <<= 1) s += __shfl_xor(s, m, 16);
        if (tid == 0) partial[blockIdx.x] = s;
    }
}

__global__ __launch_bounds__(128) void scan2_kernel(const int* __restrict__ partial,
                                                    int* __restrict__ ppref){
    __shared__ int lds[128];
    int tid = threadIdx.x;
    int v = (tid < SCAN_NB) ? partial[tid] : 0;
    lds[tid] = v;
    __syncthreads();
    for (int off = 1; off < 128; off <<= 1){
        int y = (tid >= off) ? lds[tid - off] : 0;
        __syncthreads();
        lds[tid] += y;
        __syncthreads();
    }
    if (tid < SCAN_NB) ppref[tid] = lds[tid] - v;
}

__global__ __launch_bounds__(1024) void scan3_kernel(const int* __restrict__ deg,
                                                     const int* __restrict__ ppref,
                                                     int* __restrict__ offs,
                                                     int* __restrict__ cursor){
    __shared__ int wsum[16];
    int tid = threadIdx.x, lane = tid & 63, wid = tid >> 6;
    int i = blockIdx.x * 1024 + tid;
    int v = (i < NN) ? deg[i] : 0;
    int x = v;
    #pragma unroll
    for (int off = 1; off < 64; off <<= 1){
        int y = __shfl_up(x, off);
        if (lane >= off) x += y;
    }
    if (lane == 63) wsum[wid] = x;
    __syncthreads();
    if (tid < 16){
        int s = wsum[tid];
        int t = s;
        #pragma unroll
        for (int off = 1; off < 16; off <<= 1){
            int y = __shfl_up(t, off, 16);
            if (tid >= off) t += y;
        }
        wsum[tid] = t - s;
    }
    __syncthreads();
    int base = ppref[blockIdx.x] + wsum[wid] + (x - v);
    if (i < NN){ offs[i] = base; cursor[i] = base; }
}

__global__ __launch_bounds__(256) void fill_kernel(const int* __restrict__ ei,
                                                   int* __restrict__ cursor,
                                                   int* __restrict__ ebuf){
    int e = blockIdx.x * 256 + threadIdx.x;
    if (e < EE){
        int c = ei[EE + e];
        int p = atomicAdd(&cursor[c], 1);
        ebuf[p] = ei[e];
    }
}

// ---------------- layer-weight prep: per-lane MFMA fragment layout, bf16 ----------------
__global__ __launch_bounds__(256) void wprep_kernel(const float* __restrict__ Wq,
        const float* __restrict__ Wk, const float* __restrict__ Wv,
        const float* __restrict__ Ws, u16* __restrict__ Wb2){
    int t = blockIdx.x * 256 + threadIdx.x;
    if (t >= 2 * 128 * 64) return;
    int lane = t & 63, fi = (t >> 6) & 127, l = t >> 13;
    int gnt = fi >> 2, kk = fi & 3;
    int m = gnt >> 3;
    int col = (gnt * 16 + (lane & 15)) & 127;
    const float* W = (m == 0 ? Wq : m == 1 ? Wk : m == 2 ? Wv : Ws) + (size_t)l * 16384;
    int k0 = kk * 32 + (lane >> 4) * 8;
    u16* dst = Wb2 + ((size_t)l * 128 + fi) * 512 + lane * 8;
    #pragma unroll
    for (int e = 0; e < 8; ++e) dst[e] = f2bf(W[(size_t)(k0 + e) * 128 + col]);
}

// ---------------- fused 4-matrix MFMA GEMM: out = h @ {Wq,Wk,Wv,Ws} + bias (bf16) ----------------
__global__ __launch_bounds__(256) void gemm4_mfma(const u16* __restrict__ hb,
        const u16* __restrict__ Wb2,
        const float* __restrict__ bq, const float* __restrict__ bk,
        const float* __restrict__ bv, const float* __restrict__ bs,
        u16* __restrict__ qb, u16* __restrict__ kb,
        u16* __restrict__ vb, u16* __restrict__ sb){
    __shared__ u16 hs[64 * 128];        // 16 KB, XOR-swizzled rows of 256B
    __shared__ u16 ob[4][64 * 128];     // 64 KB, per-wave repack buffers
    int tid = threadIdx.x;
    int n0  = blockIdx.x * 64;
    #pragma unroll
    for (int i = 0; i < 4; ++i){
        int c = i * 256 + tid;
        int row = c >> 4, cb = (c & 15) * 16;
        uint4 v = make_uint4(0u, 0u, 0u, 0u);
        if (n0 + row < NN)
            v = *reinterpret_cast<const uint4*>(hb + (size_t)(n0 + row) * 128 + cb / 2);
        *reinterpret_cast<uint4*>((char*)hs + row * 256 + (cb ^ ((row & 7) << 4))) = v;
    }
    __syncthreads();
    int l = tid & 63, w = tid >> 6;
    int r16 = l & 15, kq = l >> 4;
    short8 ha[4][4];
    #pragma unroll
    for (int rg = 0; rg < 4; ++rg)
        #pragma unroll
        for (int kk = 0; kk < 4; ++kk){
            int row = rg * 16 + r16;
            int byt = (kk * 64 + kq * 16) ^ ((row & 7) << 4);
            ha[rg][kk] = *reinterpret_cast<const short8*>((const char*)hs + row * 256 + byt);
        }
    const float* bp  = w == 0 ? bq : w == 1 ? bk : w == 2 ? bv : bs;
    u16*        outp = w == 0 ? qb : w == 1 ? kb : w == 2 ? vb : sb;
    const short8* wfrag = reinterpret_cast<const short8*>(Wb2) + (size_t)(w * 8) * 4 * 64;
    u16* myob = &ob[w][0];
    #pragma unroll
    for (int nt = 0; nt < 8; ++nt){
        f32x4 acc[4];
        #pragma unroll
        for (int rg = 0; rg < 4; ++rg) acc[rg] = (f32x4){0.f, 0.f, 0.f, 0.f};
        #pragma unroll
        for (int kk = 0; kk < 4; ++kk){
            short8 wf = wfrag[(nt * 4 + kk) * 64 + l];
            #pragma unroll
            for (int rg = 0; rg < 4; ++rg)
                acc[rg] = __builtin_amdgcn_mfma_f32_16x16x32_bf16(wf, ha[rg][kk], acc[rg], 0, 0, 0);
        }
        float4 bvv = *reinterpret_cast<const float4*>(bp + nt * 16 + kq * 4);
        #pragma unroll
        for (int rg = 0; rg < 4; ++rg){
            u32 p0 = pack2(acc[rg][0] + bvv.x, acc[rg][1] + bvv.y);
            u32 p1 = pack2(acc[rg][2] + bvv.z, acc[rg][3] + bvv.w);
            int row = rg * 16 + r16;
            int cb  = (nt * 32 + kq * 8) ^ ((row & 7) << 4);
            *reinterpret_cast<uint2*>((char*)myob + row * 256 + cb) = make_uint2(p0, p1);
        }
    }
    asm volatile("s_waitcnt lgkmcnt(0)" ::: "memory");
    #pragma unroll
    for (int i = 0; i < 16; ++i){
        int row = i * 4 + kq;
        int cb  = r16 * 16;
        uint4 v = *reinterpret_cast<const uint4*>((char*)myob + row * 256 + (cb ^ ((row & 7) << 4)));
        if (n0 + row < NN)
            *reinterpret_cast<uint4*>(outp + (size_t)(n0 + row) * 128 + cb / 2) = v;
    }
}

// ---------------- fused edge attention + aggregate + skip + residual + LN + ReLU ----------------
// 1 wave/node; lanes 0-31 = edge A, lanes 32-63 = edge B; 4 dims/lane (uint2).
__global__ __launch_bounds__(256) void attn_kernel(u16* __restrict__ hb,
        const u16* __restrict__ qb, const u16* __restrict__ kb,
        const u16* __restrict__ vb, const u16* __restrict__ sb,
        const int* __restrict__ offs, const int* __restrict__ deg,
        const int* __restrict__ ebuf,
        const float* __restrict__ g, const float* __restrict__ bta){
    int tid  = threadIdx.x;
    int lane = tid & 63;
    int n    = blockIdx.x * 4 + (tid >> 6);
    int half = lane >> 5, sl = lane & 31;
    const uint2 qu = *reinterpret_cast<const uint2*>(qb + (size_t)n * 128 + sl * 4);
    float q0 = bflo(qu.x), q1 = bfhi(qu.x), q2 = bflo(qu.y), q3 = bfhi(qu.y);
    int beg = offs[n], cnt = deg[n];
    float z = 0.f, a0 = 0.f, a1 = 0.f, a2 = 0.f, a3 = 0.f;
    const float scale = 0.17677669529663687f;   // 1/sqrt(32)

    #define EDGE2(rA_, rB_)                                                         \
    {   int r_ = half ? (rB_) : (rA_);                                              \
        uint2 ku = *reinterpret_cast<const uint2*>(kb + (size_t)r_ * 128 + sl * 4); \
        uint2 vu = *reinterpret_cast<const uint2*>(vb + (size_t)r_ * 128 + sl * 4); \
        float s = q0 * bflo(ku.x) + q1 * bfhi(ku.x)                                 \
                + q2 * bflo(ku.y) + q3 * bfhi(ku.y);                                \
        s += __shfl_xor(s, 1); s += __shfl_xor(s, 2); s += __shfl_xor(s, 4);        \
        float ex = __expf(s * scale);                                               \
        z += ex;                                                                    \
        a0 = fmaf(ex, bflo(vu.x), a0); a1 = fmaf(ex, bfhi(vu.x), a1);               \
        a2 = fmaf(ex, bflo(vu.y), a2); a3 = fmaf(ex, bfhi(vu.y), a3);  }

    int t = 0;
    for (; t + 4 <= cnt; t += 4){            // 4 edges in flight
        int r0 = ebuf[beg + t],     r1 = ebuf[beg + t + 1];
        int r2 = ebuf[beg + t + 2], r3 = ebuf[beg + t + 3];
        EDGE2(r0, r1);
        EDGE2(r2, r3);
    }
    if (t + 2 <= cnt){
        int r0 = ebuf[beg + t], r1 = ebuf[beg + t + 1];
        EDGE2(r0, r1);
        t += 2;
    }
    if (t < cnt){                            // tail: half A only
        int r = ebuf[beg + t];
        uint2 ku = *reinterpret_cast<const uint2*>(kb + (size_t)r * 128 + sl * 4);
        uint2 vu = *reinterpret_cast<const uint2*>(vb + (size_t)r * 128 + sl * 4);
        float s = q0 * bflo(ku.x) + q1 * bfhi(ku.x)
                + q2 * bflo(ku.y) + q3 * bfhi(ku.y);
        s += __shfl_xor(s, 1); s += __shfl_xor(s, 2); s += __shfl_xor(s, 4);
        float ex = half ? 0.f : __expf(s * scale);
        z += ex;
        a0 = fmaf(ex, bflo(vu.x), a0); a1 = fmaf(ex, bfhi(vu.x), a1);
        a2 = fmaf(ex, bflo(vu.y), a2); a3 = fmaf(ex, bfhi(vu.y), a3);
    }
    #undef EDGE2

    z  += __shfl_xor(z, 32);
    a0 += __shfl_xor(a0, 32); a1 += __shfl_xor(a1, 32);
    a2 += __shfl_xor(a2, 32); a3 += __shfl_xor(a3, 32);
    float rz = (cnt > 0) ? 1.f / z : 0.f;

    size_t p = (size_t)n * 128 + sl * 4;
    uint2 hu = *reinterpret_cast<const uint2*>(hb + p);
    uint2 su = *reinterpret_cast<const uint2*>(sb + p);
    float y0 = bflo(hu.x) + a0 * rz + bflo(su.x);
    float y1 = bfhi(hu.x) + a1 * rz + bfhi(su.x);
    float y2 = bflo(hu.y) + a2 * rz + bflo(su.y);
    float y3 = bfhi(hu.y) + a3 * rz + bfhi(su.y);
    float sum = y0 + y1 + y2 + y3;
    float sq  = y0 * y0 + y1 * y1 + y2 * y2 + y3 * y3;
    #pragma unroll
    for (int m = 1; m < 32; m <<= 1){
        sum += __shfl_xor(sum, m);
        sq  += __shfl_xor(sq,  m);
    }
    float mu  = sum * (1.f / 128.f);
    float var = sq * (1.f / 128.f) - mu * mu;
    var = var < 0.f ? 0.f : var;
    float inv = rsqrtf(var + 1e-5f);
    int c = sl * 4;
    float o0 = fmaf(g[c    ] * (y0 - mu), inv, bta[c    ]);
    float o1 = fmaf(g[c + 1] * (y1 - mu), inv, bta[c + 1]);
    float o2 = fmaf(g[c + 2] * (y2 - mu), inv, bta[c + 2]);
    float o3 = fmaf(g[c + 3] * (y3 - mu), inv, bta[c + 3]);
    o0 = o0 > 0.f ? o0 : 0.f;  o1 = o1 > 0.f ? o1 : 0.f;
    o2 = o2 > 0.f ? o2 : 0.f;  o3 = o3 > 0.f ? o3 : 0.f;
    if (!half)
        *reinterpret_cast<uint2*>(hb + p) = make_uint2(pack2(o0, o1), pack2(o2, o3));
}

// ---------------- link prediction: sigmoid(h[src] . h[dst]) (bf16) ----------------
__global__ __launch_bounds__(256) void pair_kernel(const u16* __restrict__ hb,
                                                   const int* __restrict__ src,
                                                   const int* __restrict__ dst,
                                                   float* __restrict__ out){
    int tid = threadIdx.x;
    int pid = blockIdx.x * 16 + (tid >> 4);
    int sub = tid & 15;
    int s = src[pid], d = dst[pid];
    uint4 a = *reinterpret_cast<const uint4*>(hb + (size_t)s * 128 + sub * 8);
    uint4 b = *reinterpret_cast<const uint4*>(hb + (size_t)d * 128 + sub * 8);
    float dot = bflo(a.x) * bflo(b.x) + bfhi(a.x) * bfhi(b.x)
              + bflo(a.y) * bflo(b.y) + bfhi(a.y) * bfhi(b.y)
              + bflo(a.z) * bflo(b.z) + bfhi(a.z) * bfhi(b.z)
              + bflo(a.w) * bflo(b.w) + bfhi(a.w) * bfhi(b.w);
    dot += __shfl_xor(dot, 1); dot += __shfl_xor(dot, 2);
    dot += __shfl_xor(dot, 4); dot += __shfl_xor(dot, 8);
    if (sub == 0) out[pid] = 1.f / (1.f + __expf(-dot));
}

extern "C" void kernel_launch(void* const* d_in, const int* in_sizes, int n_in,
                              void* d_out, int out_size, void* d_ws, size_t ws_size,
                              hipStream_t stream){
    const float* x      = (const float*)d_in[0];
    const float* rw     = (const float*)d_in[1];
    const int*   ei     = (const int*)  d_in[2];
    const int*   src    = (const int*)  d_in[3];
    const int*   dst    = (const int*)  d_in[4];
    const float* W_rwse = (const float*)d_in[5];
    const float* b_rwse = (const float*)d_in[6];
    const float* W_in   = (const float*)d_in[7];
    const float* b_in   = (const float*)d_in[8];
    const float* Wq     = (const float*)d_in[9];
    const float* bq     = (const float*)d_in[10];
    const float* Wk     = (const float*)d_in[11];
    const float* bk     = (const float*)d_in[12];
    const float* Wv     = (const float*)d_in[13];
    const float* bv     = (const float*)d_in[14];
    const float* Wsk    = (const float*)d_in[15];
    const float* bsk    = (const float*)d_in[16];
    const float* ln_g   = (const float*)d_in[17];
    const float* ln_b   = (const float*)d_in[18];
    float* out = (float*)d_out;

    char* p = (char*)d_ws;
    auto carve = [&](size_t bytes) -> char* {
        char* r = p; p += (bytes + 255) & ~(size_t)255; return r;
    };
    u16*   hb   = (u16*)  carve((size_t)NN * 128 * 2);   // 25.6 MB
    u16*   qb   = (u16*)  carve((size_t)NN * 128 * 2);
    u16*   kb   = (u16*)  carve((size_t)NN * 128 * 2);
    u16*   vb   = (u16*)  carve((size_t)NN * 128 * 2);
    u16*   sb   = (u16*)  carve((size_t)NN * 128 * 2);
    int*   deg  = (int*)  carve((size_t)NN * 4);
    int*   offs = (int*)  carve((size_t)NN * 4);
    int*   curs = (int*)  carve((size_t)NN * 4);
    int*   ebuf = (int*)  carve((size_t)EE * 4);
    int*   part = (int*)  carve((size_t)SCAN_NB * 4);
    int*   ppref= (int*)  carve((size_t)SCAN_NB * 4);
    u16*   Wb2  = (u16*)  carve((size_t)2 * 128 * 512 * 2);  // 256 KB
    u16*   Winb = (u16*)  carve((size_t)8 * 5 * 512 * 2);    //  40 KB

    hipMemsetAsync(deg, 0, (size_t)NN * 4, stream);

    winprep_kernel<<<10, 256, 0, stream>>>(W_in, Winb);
    wprep_kernel<<<64, 256, 0, stream>>>(Wq, Wk, Wv, Wsk, Wb2);
    inproj_mfma<<<(NN + 63) / 64, 256, 0, stream>>>(x, rw, W_rwse, b_rwse,
                                                    Winb, b_in, hb);
    deg_kernel<<<(EE + 255) / 256, 256, 0, stream>>>(ei + EE, deg);
    scan1_kernel<<<SCAN_NB, 1024, 0, stream>>>(deg, part);
    scan2_kernel<<<1, 128, 0, stream>>>(part, ppref);
    scan3_kernel<<<SCAN_NB, 1024, 0, stream>>>(deg, ppref, offs, curs);
    fill_kernel<<<(EE + 255) / 256, 256, 0, stream>>>(ei, curs, ebuf);

    for (int l = 0; l < 2; ++l){
        gemm4_mfma<<<(NN + 63) / 64, 256, 0, stream>>>(hb, Wb2 + (size_t)l * 65536,
            bq + l * 128, bk + l * 128, bv + l * 128, bsk + l * 128,
            qb, kb, vb, sb);
        attn_kernel<<<NN / 4, 256, 0, stream>>>(hb, qb, kb, vb, sb,
            offs, deg, ebuf, ln_g + l * 128, ln_b + l * 128);
    }
    pair_kernel<<<NPAIRSC / 16, 256, 0, stream>>>(hb, src, dst, out);
}